// Round 1
// baseline (500.522 us; speedup 1.0000x reference)
//
#include <hip/hip_runtime.h>
#include <hip/hip_bf16.h>
#include <cstdint>
#include <cstddef>

typedef __bf16 bf16;
typedef __attribute__((ext_vector_type(4))) float f32x4;
typedef __attribute__((ext_vector_type(8))) __bf16 bf16x8;

// ---------------- constants ----------------
#define T_TOKENS 8192
#define D_MODEL  1024
#define D_FF     2048
#define N_EXP    8
#define MAX_ROWS 17408   // 16384 + 8*128 padding
#define MAX_MT   136     // max m-tiles of 128

// ctrl layout (int indices): counts[0..7], cursors[8..15], numTiles[16],
// pstart[32..40], tileExpert[64..199], tileRow[256..391]

__device__ __forceinline__ void gload16(const void* g, void* l) {
    __builtin_amdgcn_global_load_lds((const __attribute__((address_space(1))) void*)g,
                                     (__attribute__((address_space(3))) void*)l, 16, 0, 0);
}

// ---------------- dispatch building ----------------
__global__ void count_kernel(const int* __restrict__ ei, int* __restrict__ ctrl) {
    __shared__ int lc[N_EXP];
    if (threadIdx.x < N_EXP) lc[threadIdx.x] = 0;
    __syncthreads();
    int t = blockIdx.x * blockDim.x + threadIdx.x;
    if (t < T_TOKENS) {
        atomicAdd(&lc[ei[t * 2 + 0]], 1);
        atomicAdd(&lc[ei[t * 2 + 1]], 1);
    }
    __syncthreads();
    if (threadIdx.x < N_EXP) atomicAdd(&ctrl[threadIdx.x], lc[threadIdx.x]);
}

__global__ void scan_kernel(int* __restrict__ ctrl, int* __restrict__ tokenId,
                            float* __restrict__ rowW) {
    if (threadIdx.x == 0) {
        int s = 0, nt = 0;
        for (int e = 0; e < N_EXP; ++e) {
            ctrl[32 + e] = s;
            int cnt = ctrl[e];
            int tiles = (cnt + 127) >> 7;
            for (int i = 0; i < tiles; ++i) { ctrl[64 + nt] = e; ctrl[256 + nt] = s + (i << 7); ++nt; }
            s += tiles << 7;
        }
        ctrl[32 + 8] = s;
        ctrl[16] = nt;
    }
    for (int r = threadIdx.x; r < MAX_ROWS; r += blockDim.x) { tokenId[r] = 0; rowW[r] = 0.f; }
}

__global__ void scatter_kernel(const int* __restrict__ ei, const float* __restrict__ ew,
                               int* __restrict__ ctrl, int* __restrict__ tokenId,
                               float* __restrict__ rowW) {
    int t = blockIdx.x * blockDim.x + threadIdx.x;
    if (t >= T_TOKENS) return;
    for (int k = 0; k < 2; ++k) {
        int e = ei[t * 2 + k];
        int pos = atomicAdd(&ctrl[8 + e], 1);
        int r = ctrl[32 + e] + pos;
        tokenId[r] = t;
        rowW[r] = ew[t * 2 + k];
    }
}

// ---------------- conversions ----------------
__global__ void cvtx_kernel(const float* __restrict__ x, bf16* __restrict__ xb) {
    int i = (blockIdx.x * 256 + threadIdx.x) * 4;
    float4 v = *(const float4*)(x + i);
    bf16x8 o;  // use low 4
    o[0] = (bf16)v.x; o[1] = (bf16)v.y; o[2] = (bf16)v.z; o[3] = (bf16)v.w;
    *(uint2*)(xb + i) = *(uint2*)&o;
}

// transpose-convert: in fp32 [E][R][C] -> out bf16 [E][C][R]
__global__ void tconv_kernel(const float* __restrict__ in, bf16* __restrict__ out,
                             int R, int C) {
    __shared__ float tile[32][33];
    size_t mat = (size_t)R * C;
    const float* src = in + mat * blockIdx.z;
    bf16* dst = out + mat * blockIdx.z;
    int c0 = blockIdx.x * 32, r0 = blockIdx.y * 32;
    int tx = threadIdx.x & 31, ty = threadIdx.x >> 5;  // ty 0..7
#pragma unroll
    for (int p = 0; p < 4; ++p)
        tile[ty + 8 * p][tx] = src[(size_t)(r0 + ty + 8 * p) * C + c0 + tx];
    __syncthreads();
#pragma unroll
    for (int p = 0; p < 4; ++p)
        dst[(size_t)(c0 + ty + 8 * p) * R + r0 + tx] = (bf16)tile[tx][ty + 8 * p];
}

// ---------------- GEMM stage 1: H = silu(X W1) * (X W2), gathered rows ----------------
__global__ __launch_bounds__(256, 2)
void gemm1_kernel(const bf16* __restrict__ xb, const bf16* __restrict__ w1t,
                  const bf16* __restrict__ w2t, bf16* __restrict__ H,
                  const int* __restrict__ ctrl, const int* __restrict__ tokenId) {
    const int mt = blockIdx.y;
    if (mt >= ctrl[16]) return;
    const int e = ctrl[64 + mt];
    const int rowBase = ctrl[256 + mt];
    const int n0 = blockIdx.x * 128;

    __shared__ bf16 As[128 * 64];
    __shared__ bf16 B1s[128 * 64];
    __shared__ bf16 B2s[128 * 64];

    const int tid = threadIdx.x, lane = tid & 63;
    const int wm = (tid >> 7) & 1, wn = (tid >> 6) & 1;

    const bf16* w1b = w1t + (size_t)e * D_FF * D_MODEL;
    const bf16* w2b = w2t + (size_t)e * D_FF * D_MODEL;

    const bf16* aSrc[4]; const bf16* b1Src[4]; const bf16* b2Src[4]; int dstOff[4];
#pragma unroll
    for (int rd = 0; rd < 4; ++rd) {
        int o = rd * 4096 + tid * 16;
        int r = o >> 7;
        int c2 = ((o >> 4) & 7) ^ (r & 7);
        dstOff[rd] = o;
        int tok = tokenId[rowBase + r];
        aSrc[rd]  = xb  + (size_t)tok * D_MODEL + c2 * 8;
        b1Src[rd] = w1b + (size_t)(n0 + r) * D_MODEL + c2 * 8;
        b2Src[rd] = w2b + (size_t)(n0 + r) * D_MODEL + c2 * 8;
    }

    f32x4 accG[4][4], accV[4][4];
#pragma unroll
    for (int m = 0; m < 4; ++m)
#pragma unroll
        for (int n = 0; n < 4; ++n) { accG[m][n] = (f32x4){0.f,0.f,0.f,0.f}; accV[m][n] = (f32x4){0.f,0.f,0.f,0.f}; }

    char* AsB = (char*)As; char* B1B = (char*)B1s; char* B2B = (char*)B2s;

    for (int kt = 0; kt < D_MODEL / 64; ++kt) {
        __syncthreads();
#pragma unroll
        for (int rd = 0; rd < 4; ++rd) {
            gload16(aSrc[rd]  + kt * 64, AsB + dstOff[rd]);
            gload16(b1Src[rd] + kt * 64, B1B + dstOff[rd]);
            gload16(b2Src[rd] + kt * 64, B2B + dstOff[rd]);
        }
        __syncthreads();
#pragma unroll
        for (int ks = 0; ks < 2; ++ks) {
            bf16x8 af[4], b1f[4], b2f[4];
            int c2 = ks * 4 + (lane >> 4);
#pragma unroll
            for (int m = 0; m < 4; ++m) {
                int r = wm * 64 + m * 16 + (lane & 15);
                af[m] = *(const bf16x8*)(AsB + r * 128 + ((c2 ^ (r & 7)) << 4));
            }
#pragma unroll
            for (int n = 0; n < 4; ++n) {
                int r = wn * 64 + n * 16 + (lane & 15);
                int off = r * 128 + ((c2 ^ (r & 7)) << 4);
                b1f[n] = *(const bf16x8*)(B1B + off);
                b2f[n] = *(const bf16x8*)(B2B + off);
            }
#pragma unroll
            for (int m = 0; m < 4; ++m)
#pragma unroll
                for (int n = 0; n < 4; ++n) {
                    accG[m][n] = __builtin_amdgcn_mfma_f32_16x16x32_bf16(af[m], b1f[n], accG[m][n], 0, 0, 0);
                    accV[m][n] = __builtin_amdgcn_mfma_f32_16x16x32_bf16(af[m], b2f[n], accV[m][n], 0, 0, 0);
                }
        }
    }

#pragma unroll
    for (int m = 0; m < 4; ++m) {
#pragma unroll
        for (int j = 0; j < 4; ++j) {
            int rl = wm * 64 + m * 16 + (lane >> 4) * 4 + j;
            size_t rowOffset = (size_t)(rowBase + rl) * D_FF;
#pragma unroll
            for (int n = 0; n < 4; ++n) {
                int col = n0 + wn * 64 + n * 16 + (lane & 15);
                float g = accG[m][n][j];
                float v = accV[m][n][j];
                float hv = (g / (1.f + __expf(-g))) * v;
                H[rowOffset + col] = (bf16)hv;
            }
        }
    }
}

// ---------------- GEMM stage 2: out[tok] += w * (H @ W3) ----------------
__global__ __launch_bounds__(256, 2)
void gemm2_kernel(const bf16* __restrict__ H, const bf16* __restrict__ w3t,
                  float* __restrict__ out, const int* __restrict__ ctrl,
                  const int* __restrict__ tokenId, const float* __restrict__ rowW) {
    const int mt = blockIdx.y;
    if (mt >= ctrl[16]) return;
    const int e = ctrl[64 + mt];
    const int rowBase = ctrl[256 + mt];
    const int n0 = blockIdx.x * 128;

    __shared__ bf16 As[128 * 64];
    __shared__ bf16 Bs[128 * 64];

    const int tid = threadIdx.x, lane = tid & 63;
    const int wm = (tid >> 7) & 1, wn = (tid >> 6) & 1;

    const bf16* w3b = w3t + (size_t)e * D_MODEL * D_FF;
    const bf16* aSrc[4]; const bf16* bSrc[4]; int dstOff[4];
#pragma unroll
    for (int rd = 0; rd < 4; ++rd) {
        int o = rd * 4096 + tid * 16;
        int r = o >> 7;
        int c2 = ((o >> 4) & 7) ^ (r & 7);
        dstOff[rd] = o;
        aSrc[rd] = H   + (size_t)(rowBase + r) * D_FF + c2 * 8;
        bSrc[rd] = w3b + (size_t)(n0 + r) * D_FF + c2 * 8;
    }

    f32x4 acc[4][4];
#pragma unroll
    for (int m = 0; m < 4; ++m)
#pragma unroll
        for (int n = 0; n < 4; ++n) acc[m][n] = (f32x4){0.f,0.f,0.f,0.f};

    char* AsB = (char*)As; char* BsB = (char*)Bs;

    for (int kt = 0; kt < D_FF / 64; ++kt) {
        __syncthreads();
#pragma unroll
        for (int rd = 0; rd < 4; ++rd) {
            gload16(aSrc[rd] + kt * 64, AsB + dstOff[rd]);
            gload16(bSrc[rd] + kt * 64, BsB + dstOff[rd]);
        }
        __syncthreads();
#pragma unroll
        for (int ks = 0; ks < 2; ++ks) {
            bf16x8 af[4], bf[4];
            int c2 = ks * 4 + (lane >> 4);
#pragma unroll
            for (int m = 0; m < 4; ++m) {
                int r = wm * 64 + m * 16 + (lane & 15);
                af[m] = *(const bf16x8*)(AsB + r * 128 + ((c2 ^ (r & 7)) << 4));
            }
#pragma unroll
            for (int n = 0; n < 4; ++n) {
                int r = wn * 64 + n * 16 + (lane & 15);
                bf[n] = *(const bf16x8*)(BsB + r * 128 + ((c2 ^ (r & 7)) << 4));
            }
#pragma unroll
            for (int m = 0; m < 4; ++m)
#pragma unroll
                for (int n = 0; n < 4; ++n)
                    acc[m][n] = __builtin_amdgcn_mfma_f32_16x16x32_bf16(af[m], bf[n], acc[m][n], 0, 0, 0);
        }
    }

#pragma unroll
    for (int m = 0; m < 4; ++m) {
#pragma unroll
        for (int j = 0; j < 4; ++j) {
            int rl = wm * 64 + m * 16 + (lane >> 4) * 4 + j;
            int row = rowBase + rl;
            int tok = tokenId[row];
            float wgt = rowW[row];
            float* obase = out + (size_t)tok * D_MODEL + n0 + wn * 64 + (lane & 15);
#pragma unroll
            for (int n = 0; n < 4; ++n)
                atomicAdd(obase + n * 16, wgt * acc[m][n][j]);
        }
    }
}

// ---------------- launch ----------------
extern "C" void kernel_launch(void* const* d_in, const int* in_sizes, int n_in,
                              void* d_out, int out_size, void* d_ws, size_t ws_size,
                              hipStream_t stream) {
    const float* x  = (const float*)d_in[0];
    const int*   ei = (const int*)d_in[1];
    const float* ew = (const float*)d_in[2];
    const float* w1 = (const float*)d_in[3];
    const float* w2 = (const float*)d_in[4];
    const float* w3 = (const float*)d_in[5];
    float* out = (float*)d_out;

    char* w = (char*)d_ws;
    constexpr size_t CTRL_OFF = 0;
    constexpr size_t TOK_OFF  = 4096;
    constexpr size_t ROWW_OFF = TOK_OFF + MAX_ROWS * 4;            // 73728
    constexpr size_t XB_OFF   = 143360;                            // 256-aligned
    constexpr size_t W1T_OFF  = XB_OFF + (size_t)T_TOKENS * D_MODEL * 2;
    constexpr size_t W2T_OFF  = W1T_OFF + (size_t)N_EXP * D_MODEL * D_FF * 2;
    constexpr size_t W3T_OFF  = W2T_OFF + (size_t)N_EXP * D_MODEL * D_FF * 2;
    constexpr size_t H_OFF    = W3T_OFF + (size_t)N_EXP * D_MODEL * D_FF * 2;

    int*   ctrl    = (int*)(w + CTRL_OFF);
    int*   tokenId = (int*)(w + TOK_OFF);
    float* rowW    = (float*)(w + ROWW_OFF);
    bf16*  xb      = (bf16*)(w + XB_OFF);
    bf16*  w1t     = (bf16*)(w + W1T_OFF);
    bf16*  w2t     = (bf16*)(w + W2T_OFF);
    bf16*  w3t     = (bf16*)(w + W3T_OFF);
    bf16*  H       = (bf16*)(w + H_OFF);

    hipMemsetAsync(ctrl, 0, 64, stream);  // counts + cursors
    hipMemsetAsync(d_out, 0, (size_t)out_size * sizeof(float), stream);

    count_kernel<<<T_TOKENS / 256, 256, 0, stream>>>(ei, ctrl);
    scan_kernel<<<1, 256, 0, stream>>>(ctrl, tokenId, rowW);
    scatter_kernel<<<T_TOKENS / 256, 256, 0, stream>>>(ei, ew, ctrl, tokenId, rowW);

    cvtx_kernel<<<(T_TOKENS * D_MODEL) / (256 * 4), 256, 0, stream>>>(x, xb);
    tconv_kernel<<<dim3(D_FF / 32, D_MODEL / 32, N_EXP), 256, 0, stream>>>(w1, w1t, D_MODEL, D_FF);
    tconv_kernel<<<dim3(D_FF / 32, D_MODEL / 32, N_EXP), 256, 0, stream>>>(w2, w2t, D_MODEL, D_FF);
    tconv_kernel<<<dim3(D_MODEL / 32, D_FF / 32, N_EXP), 256, 0, stream>>>(w3, w3t, D_FF, D_MODEL);

    gemm1_kernel<<<dim3(D_FF / 128, MAX_MT), 256, 0, stream>>>(xb, w1t, w2t, H, ctrl, tokenId);
    gemm2_kernel<<<dim3(D_MODEL / 128, MAX_MT), 256, 0, stream>>>(H, w3t, out, ctrl, tokenId, rowW);
}

// Round 3
// 425.442 us; speedup vs baseline: 1.1765x; 1.1765x over previous
//
#include <hip/hip_runtime.h>
#include <hip/hip_bf16.h>
#include <cstdint>
#include <cstddef>

typedef __bf16 bf16;
typedef __attribute__((ext_vector_type(4))) float f32x4;
typedef __attribute__((ext_vector_type(8))) __bf16 bf16x8;
typedef __attribute__((ext_vector_type(4))) __bf16 bf16x4;

// ---------------- constants ----------------
#define T_TOKENS 8192
#define D_MODEL  1024
#define D_FF     2048
#define N_EXP    8
#define MAX_ROWS 17408   // 16384 + 8*128 padding
#define MAX_MT   136     // max m-tiles of 128

// ctrl layout (int indices): counts[0..7], cursors[8..15], numTiles[16],
// pstart[32..40], tileExpert[64..199], tileRow[256..391]

__device__ __forceinline__ void gload16(const void* g, void* l) {
    __builtin_amdgcn_global_load_lds((const __attribute__((address_space(1))) void*)g,
                                     (__attribute__((address_space(3))) void*)l, 16, 0, 0);
}

// ---------------- dispatch building ----------------
__global__ void count_kernel(const int* __restrict__ ei, int* __restrict__ ctrl) {
    __shared__ int lc[N_EXP];
    if (threadIdx.x < N_EXP) lc[threadIdx.x] = 0;
    __syncthreads();
    int t = blockIdx.x * blockDim.x + threadIdx.x;
    if (t < T_TOKENS) {
        atomicAdd(&lc[ei[t * 2 + 0]], 1);
        atomicAdd(&lc[ei[t * 2 + 1]], 1);
    }
    __syncthreads();
    if (threadIdx.x < N_EXP) atomicAdd(&ctrl[threadIdx.x], lc[threadIdx.x]);
}

__global__ void scan_kernel(int* __restrict__ ctrl, int* __restrict__ tokenId,
                            float* __restrict__ rowW) {
    if (threadIdx.x == 0) {
        int s = 0, nt = 0;
        for (int e = 0; e < N_EXP; ++e) {
            ctrl[32 + e] = s;
            int cnt = ctrl[e];
            int tiles = (cnt + 127) >> 7;
            for (int i = 0; i < tiles; ++i) { ctrl[64 + nt] = e; ctrl[256 + nt] = s + (i << 7); ++nt; }
            s += tiles << 7;
        }
        ctrl[32 + 8] = s;
        ctrl[16] = nt;
    }
    for (int r = threadIdx.x; r < MAX_ROWS; r += blockDim.x) { tokenId[r] = 0; rowW[r] = 0.f; }
}

__global__ void scatter_kernel(const int* __restrict__ ei, const float* __restrict__ ew,
                               int* __restrict__ ctrl, int* __restrict__ tokenId,
                               float* __restrict__ rowW, int* __restrict__ rowOf) {
    int t = blockIdx.x * blockDim.x + threadIdx.x;
    if (t >= T_TOKENS) return;
    for (int k = 0; k < 2; ++k) {
        int e = ei[t * 2 + k];
        int pos = atomicAdd(&ctrl[8 + e], 1);
        int r = ctrl[32 + e] + pos;
        tokenId[r] = t;
        rowW[r] = ew[t * 2 + k];
        rowOf[t * 2 + k] = r;
    }
}

// ---------------- conversions ----------------
__global__ void cvtx_kernel(const float* __restrict__ x, bf16* __restrict__ xb) {
    int i = (blockIdx.x * 256 + threadIdx.x) * 8;
    float4 v0 = *(const float4*)(x + i);
    float4 v1 = *(const float4*)(x + i + 4);
    bf16x8 o;
    o[0] = (bf16)v0.x; o[1] = (bf16)v0.y; o[2] = (bf16)v0.z; o[3] = (bf16)v0.w;
    o[4] = (bf16)v1.x; o[5] = (bf16)v1.y; o[6] = (bf16)v1.z; o[7] = (bf16)v1.w;
    *(bf16x8*)(xb + i) = o;
}

// transpose-convert: in fp32 [E][R][C] -> out bf16 [E][C][R]
__global__ void tconv_kernel(const float* __restrict__ in, bf16* __restrict__ out,
                             int R, int C) {
    __shared__ float tile[32][33];
    size_t mat = (size_t)R * C;
    const float* src = in + mat * blockIdx.z;
    bf16* dst = out + mat * blockIdx.z;
    int c0 = blockIdx.x * 32, r0 = blockIdx.y * 32;
    int tx = threadIdx.x & 31, ty = threadIdx.x >> 5;  // ty 0..7
#pragma unroll
    for (int p = 0; p < 4; ++p)
        tile[ty + 8 * p][tx] = src[(size_t)(r0 + ty + 8 * p) * C + c0 + tx];
    __syncthreads();
    // packed writes: 512 uint writes (2 bf16 each), 2 per thread
#pragma unroll
    for (int p = 0; p < 2; ++p) {
        int w = threadIdx.x + 256 * p;
        int col = w >> 4;          // 0..31
        int pr  = w & 15;          // row pair
        bf16 lo = (bf16)tile[2 * pr][col];
        bf16 hi = (bf16)tile[2 * pr + 1][col];
        uint32_t pk = ((uint32_t)*(uint16_t*)&hi << 16) | *(uint16_t*)&lo;
        *(uint32_t*)(dst + (size_t)(c0 + col) * R + r0 + 2 * pr) = pk;
    }
}

// ---------------- GEMM stage 1: H = silu(X W1) * (X W2), gathered rows ----------------
__global__ __launch_bounds__(256, 2)
void gemm1_kernel(const bf16* __restrict__ xb, const bf16* __restrict__ w1t,
                  const bf16* __restrict__ w2t, bf16* __restrict__ H,
                  const int* __restrict__ ctrl, const int* __restrict__ tokenId) {
    const int mt = blockIdx.y;
    if (mt >= ctrl[16]) return;
    const int e = ctrl[64 + mt];
    const int rowBase = ctrl[256 + mt];
    const int n0 = blockIdx.x * 128;

    __shared__ bf16 As[128 * 64];
    __shared__ bf16 B1s[128 * 64];
    __shared__ bf16 B2s[128 * 64];

    const int tid = threadIdx.x, lane = tid & 63;
    const int wm = (tid >> 7) & 1, wn = (tid >> 6) & 1;

    const bf16* w1b = w1t + (size_t)e * D_FF * D_MODEL;
    const bf16* w2b = w2t + (size_t)e * D_FF * D_MODEL;

    const bf16* aSrc[4]; const bf16* b1Src[4]; const bf16* b2Src[4]; int dstOff[4];
#pragma unroll
    for (int rd = 0; rd < 4; ++rd) {
        int o = rd * 4096 + tid * 16;
        int r = o >> 7;
        int c2 = ((o >> 4) & 7) ^ (r & 7);
        dstOff[rd] = o;
        int tok = tokenId[rowBase + r];
        aSrc[rd]  = xb  + (size_t)tok * D_MODEL + c2 * 8;
        b1Src[rd] = w1b + (size_t)(n0 + r) * D_MODEL + c2 * 8;
        b2Src[rd] = w2b + (size_t)(n0 + r) * D_MODEL + c2 * 8;
    }

    f32x4 accG[4][4], accV[4][4];
#pragma unroll
    for (int m = 0; m < 4; ++m)
#pragma unroll
        for (int n = 0; n < 4; ++n) { accG[m][n] = (f32x4){0.f,0.f,0.f,0.f}; accV[m][n] = (f32x4){0.f,0.f,0.f,0.f}; }

    char* AsB = (char*)As; char* B1B = (char*)B1s; char* B2B = (char*)B2s;

    for (int kt = 0; kt < D_MODEL / 64; ++kt) {
        __syncthreads();
#pragma unroll
        for (int rd = 0; rd < 4; ++rd) {
            gload16(aSrc[rd]  + kt * 64, AsB + dstOff[rd]);
            gload16(b1Src[rd] + kt * 64, B1B + dstOff[rd]);
            gload16(b2Src[rd] + kt * 64, B2B + dstOff[rd]);
        }
        __syncthreads();
#pragma unroll
        for (int ks = 0; ks < 2; ++ks) {
            bf16x8 af[4], b1f[4], b2f[4];
            int c2 = ks * 4 + (lane >> 4);
#pragma unroll
            for (int m = 0; m < 4; ++m) {
                int r = wm * 64 + m * 16 + (lane & 15);
                af[m] = *(const bf16x8*)(AsB + r * 128 + ((c2 ^ (r & 7)) << 4));
            }
#pragma unroll
            for (int n = 0; n < 4; ++n) {
                int r = wn * 64 + n * 16 + (lane & 15);
                int off = r * 128 + ((c2 ^ (r & 7)) << 4);
                b1f[n] = *(const bf16x8*)(B1B + off);
                b2f[n] = *(const bf16x8*)(B2B + off);
            }
#pragma unroll
            for (int m = 0; m < 4; ++m)
#pragma unroll
                for (int n = 0; n < 4; ++n) {
                    accG[m][n] = __builtin_amdgcn_mfma_f32_16x16x32_bf16(af[m], b1f[n], accG[m][n], 0, 0, 0);
                    accV[m][n] = __builtin_amdgcn_mfma_f32_16x16x32_bf16(af[m], b2f[n], accV[m][n], 0, 0, 0);
                }
        }
    }

#pragma unroll
    for (int m = 0; m < 4; ++m) {
#pragma unroll
        for (int j = 0; j < 4; ++j) {
            int rl = wm * 64 + m * 16 + (lane >> 4) * 4 + j;
            size_t rowOffset = (size_t)(rowBase + rl) * D_FF;
#pragma unroll
            for (int n = 0; n < 4; ++n) {
                int col = n0 + wn * 64 + n * 16 + (lane & 15);
                float g = accG[m][n][j];
                float v = accV[m][n][j];
                float hv = (g / (1.f + __expf(-g))) * v;
                H[rowOffset + col] = (bf16)hv;
            }
        }
    }
}

// ---------------- GEMM stage 2: O2[row] = w[row] * (H[row] @ W3) ----------------
__global__ __launch_bounds__(256, 3)
void gemm2_kernel(const bf16* __restrict__ H, const bf16* __restrict__ w3t,
                  bf16* __restrict__ O2, const int* __restrict__ ctrl,
                  const float* __restrict__ rowW) {
    const int mt = blockIdx.y;
    if (mt >= ctrl[16]) return;
    const int e = ctrl[64 + mt];
    const int rowBase = ctrl[256 + mt];
    const int n0 = blockIdx.x * 128;

    __shared__ bf16 As[128 * 64];
    __shared__ bf16 Bs[128 * 64];

    const int tid = threadIdx.x, lane = tid & 63;
    const int wm = (tid >> 7) & 1, wn = (tid >> 6) & 1;

    const bf16* w3b = w3t + (size_t)e * D_MODEL * D_FF;
    const bf16* aSrc[4]; const bf16* bSrc[4]; int dstOff[4];
#pragma unroll
    for (int rd = 0; rd < 4; ++rd) {
        int o = rd * 4096 + tid * 16;
        int r = o >> 7;
        int c2 = ((o >> 4) & 7) ^ (r & 7);
        dstOff[rd] = o;
        aSrc[rd] = H   + (size_t)(rowBase + r) * D_FF + c2 * 8;
        bSrc[rd] = w3b + (size_t)(n0 + r) * D_FF + c2 * 8;
    }

    f32x4 acc[4][4];
#pragma unroll
    for (int m = 0; m < 4; ++m)
#pragma unroll
        for (int n = 0; n < 4; ++n) acc[m][n] = (f32x4){0.f,0.f,0.f,0.f};

    char* AsB = (char*)As; char* BsB = (char*)Bs;

    for (int kt = 0; kt < D_FF / 64; ++kt) {
        __syncthreads();
#pragma unroll
        for (int rd = 0; rd < 4; ++rd) {
            gload16(aSrc[rd] + kt * 64, AsB + dstOff[rd]);
            gload16(bSrc[rd] + kt * 64, BsB + dstOff[rd]);
        }
        __syncthreads();
#pragma unroll
        for (int ks = 0; ks < 2; ++ks) {
            bf16x8 af[4], bf[4];
            int c2 = ks * 4 + (lane >> 4);
#pragma unroll
            for (int m = 0; m < 4; ++m) {
                int r = wm * 64 + m * 16 + (lane & 15);
                af[m] = *(const bf16x8*)(AsB + r * 128 + ((c2 ^ (r & 7)) << 4));
            }
#pragma unroll
            for (int n = 0; n < 4; ++n) {
                int r = wn * 64 + n * 16 + (lane & 15);
                bf[n] = *(const bf16x8*)(BsB + r * 128 + ((c2 ^ (r & 7)) << 4));
            }
#pragma unroll
            for (int m = 0; m < 4; ++m)
#pragma unroll
                for (int n = 0; n < 4; ++n)
                    acc[m][n] = __builtin_amdgcn_mfma_f32_16x16x32_bf16(af[m], bf[n], acc[m][n], 0, 0, 0);
        }
    }

#pragma unroll
    for (int m = 0; m < 4; ++m) {
#pragma unroll
        for (int j = 0; j < 4; ++j) {
            int rl = wm * 64 + m * 16 + (lane >> 4) * 4 + j;
            int row = rowBase + rl;
            float wgt = rowW[row];
            bf16* obase = O2 + (size_t)row * D_MODEL + n0 + wn * 64 + (lane & 15);
#pragma unroll
            for (int n = 0; n < 4; ++n)
                obase[n * 16] = (bf16)(wgt * acc[m][n][j]);
        }
    }
}

// ---------------- combine: out[t] = O2[rowOf[t,0]] + O2[rowOf[t,1]] ----------------
__global__ void combine_kernel(const bf16* __restrict__ O2, const int* __restrict__ rowOf,
                               float* __restrict__ out) {
    int t = blockIdx.x;
    int r0 = rowOf[t * 2 + 0], r1 = rowOf[t * 2 + 1];
    int c = threadIdx.x * 4;
    bf16x4 a = *(const bf16x4*)(O2 + (size_t)r0 * D_MODEL + c);
    bf16x4 b = *(const bf16x4*)(O2 + (size_t)r1 * D_MODEL + c);
    float4 o;
    o.x = (float)a[0] + (float)b[0];
    o.y = (float)a[1] + (float)b[1];
    o.z = (float)a[2] + (float)b[2];
    o.w = (float)a[3] + (float)b[3];
    *(float4*)(out + (size_t)t * D_MODEL + c) = o;
}

// ---------------- launch ----------------
extern "C" void kernel_launch(void* const* d_in, const int* in_sizes, int n_in,
                              void* d_out, int out_size, void* d_ws, size_t ws_size,
                              hipStream_t stream) {
    const float* x  = (const float*)d_in[0];
    const int*   ei = (const int*)d_in[1];
    const float* ew = (const float*)d_in[2];
    const float* w1 = (const float*)d_in[3];
    const float* w2 = (const float*)d_in[4];
    const float* w3 = (const float*)d_in[5];
    float* out = (float*)d_out;

    char* w = (char*)d_ws;
    constexpr size_t CTRL_OFF  = 0;
    constexpr size_t TOK_OFF   = 4096;
    constexpr size_t ROWW_OFF  = TOK_OFF + (size_t)MAX_ROWS * 4;      // 73728
    constexpr size_t ROWOF_OFF = ROWW_OFF + (size_t)MAX_ROWS * 4;     // 143360
    constexpr size_t XB_OFF    = ROWOF_OFF + (size_t)T_TOKENS * 2 * 4; // 274432 (256-aligned)
    constexpr size_t W1T_OFF   = XB_OFF + (size_t)T_TOKENS * D_MODEL * 2;
    constexpr size_t W2T_OFF   = W1T_OFF + (size_t)N_EXP * D_MODEL * D_FF * 2;
    constexpr size_t W3T_OFF   = W2T_OFF + (size_t)N_EXP * D_MODEL * D_FF * 2;
    constexpr size_t H_OFF     = W3T_OFF + (size_t)N_EXP * D_MODEL * D_FF * 2;
    // O2 (bf16, MAX_ROWS x D_MODEL = 35.7 MB) aliases w1t/w2t (64 MB), which are
    // dead after gemm1 completes (stream-ordered before gemm2 writes O2).
    constexpr size_t O2_OFF    = W1T_OFF;

    int*   ctrl    = (int*)(w + CTRL_OFF);
    int*   tokenId = (int*)(w + TOK_OFF);
    float* rowW    = (float*)(w + ROWW_OFF);
    int*   rowOf   = (int*)(w + ROWOF_OFF);
    bf16*  xb      = (bf16*)(w + XB_OFF);
    bf16*  w1t     = (bf16*)(w + W1T_OFF);
    bf16*  w2t     = (bf16*)(w + W2T_OFF);
    bf16*  w3t     = (bf16*)(w + W3T_OFF);
    bf16*  H       = (bf16*)(w + H_OFF);
    bf16*  O2      = (bf16*)(w + O2_OFF);

    hipMemsetAsync(ctrl, 0, 64, stream);  // counts + cursors

    count_kernel<<<T_TOKENS / 256, 256, 0, stream>>>(ei, ctrl);
    scan_kernel<<<1, 256, 0, stream>>>(ctrl, tokenId, rowW);
    scatter_kernel<<<T_TOKENS / 256, 256, 0, stream>>>(ei, ew, ctrl, tokenId, rowW, rowOf);

    cvtx_kernel<<<(T_TOKENS * D_MODEL) / (256 * 8), 256, 0, stream>>>(x, xb);
    tconv_kernel<<<dim3(D_FF / 32, D_MODEL / 32, N_EXP), 256, 0, stream>>>(w1, w1t, D_MODEL, D_FF);
    tconv_kernel<<<dim3(D_FF / 32, D_MODEL / 32, N_EXP), 256, 0, stream>>>(w2, w2t, D_MODEL, D_FF);
    tconv_kernel<<<dim3(D_MODEL / 32, D_FF / 32, N_EXP), 256, 0, stream>>>(w3, w3t, D_FF, D_MODEL);

    gemm1_kernel<<<dim3(D_FF / 128, MAX_MT), 256, 0, stream>>>(xb, w1t, w2t, H, ctrl, tokenId);
    gemm2_kernel<<<dim3(D_MODEL / 128, MAX_MT), 256, 0, stream>>>(H, w3t, O2, ctrl, rowW);
    combine_kernel<<<T_TOKENS, 256, 0, stream>>>(O2, rowOf, out);
}

// Round 5
// 416.913 us; speedup vs baseline: 1.2005x; 1.0205x over previous
//
#include <hip/hip_runtime.h>
#include <hip/hip_bf16.h>
#include <cstdint>
#include <cstddef>

typedef __bf16 bf16;
typedef __attribute__((ext_vector_type(4))) float f32x4;
typedef __attribute__((ext_vector_type(8))) __bf16 bf16x8;
typedef __attribute__((ext_vector_type(4))) __bf16 bf16x4;

// ---------------- constants ----------------
#define T_TOKENS 8192
#define D_MODEL  1024
#define D_FF     2048
#define N_EXP    8
#define MAX_ROWS 17408   // 16384 + 8*128 padding
#define MAX_MT   136     // max m-tiles of 128

// ctrl layout (int indices): counts[0..7], cursors[8..15], numTiles[16],
// pstart[32..40], tileExpert[64..199], tileRow[256..391]

__device__ __forceinline__ void gload16(const void* g, void* l) {
    __builtin_amdgcn_global_load_lds((const __attribute__((address_space(1))) void*)g,
                                     (__attribute__((address_space(3))) void*)l, 16, 0, 0);
}

// ---------------- dispatch building ----------------
__global__ void count_kernel(const int* __restrict__ ei, int* __restrict__ ctrl) {
    __shared__ int lc[N_EXP];
    if (threadIdx.x < N_EXP) lc[threadIdx.x] = 0;
    __syncthreads();
    int t = blockIdx.x * blockDim.x + threadIdx.x;
    if (t < T_TOKENS) {
        atomicAdd(&lc[ei[t * 2 + 0]], 1);
        atomicAdd(&lc[ei[t * 2 + 1]], 1);
    }
    __syncthreads();
    if (threadIdx.x < N_EXP) atomicAdd(&ctrl[threadIdx.x], lc[threadIdx.x]);
}

__global__ void scan_kernel(int* __restrict__ ctrl, int* __restrict__ tokenId,
                            float* __restrict__ rowW) {
    if (threadIdx.x == 0) {
        int s = 0, nt = 0;
        for (int e = 0; e < N_EXP; ++e) {
            ctrl[32 + e] = s;
            int cnt = ctrl[e];
            int tiles = (cnt + 127) >> 7;
            for (int i = 0; i < tiles; ++i) { ctrl[64 + nt] = e; ctrl[256 + nt] = s + (i << 7); ++nt; }
            s += tiles << 7;
        }
        ctrl[32 + 8] = s;
        ctrl[16] = nt;
    }
    for (int r = threadIdx.x; r < MAX_ROWS; r += blockDim.x) { tokenId[r] = 0; rowW[r] = 0.f; }
}

__global__ void scatter_kernel(const int* __restrict__ ei, const float* __restrict__ ew,
                               int* __restrict__ ctrl, int* __restrict__ tokenId,
                               float* __restrict__ rowW, int* __restrict__ rowOf) {
    int t = blockIdx.x * blockDim.x + threadIdx.x;
    if (t >= T_TOKENS) return;
    for (int k = 0; k < 2; ++k) {
        int e = ei[t * 2 + k];
        int pos = atomicAdd(&ctrl[8 + e], 1);
        int r = ctrl[32 + e] + pos;
        tokenId[r] = t;
        rowW[r] = ew[t * 2 + k];
        rowOf[t * 2 + k] = r;
    }
}

// ---------------- conversions ----------------
__global__ void cvtx_kernel(const float* __restrict__ x, bf16* __restrict__ xb) {
    int i = (blockIdx.x * 256 + threadIdx.x) * 8;
    float4 v0 = *(const float4*)(x + i);
    float4 v1 = *(const float4*)(x + i + 4);
    bf16x8 o;
    o[0] = (bf16)v0.x; o[1] = (bf16)v0.y; o[2] = (bf16)v0.z; o[3] = (bf16)v0.w;
    o[4] = (bf16)v1.x; o[5] = (bf16)v1.y; o[6] = (bf16)v1.z; o[7] = (bf16)v1.w;
    *(bf16x8*)(xb + i) = o;
}

// transpose-convert: in fp32 [E][R][C] -> out bf16 [E][f(C)][R]
// mode 0: f(c)=c (plain). mode 1: f(c)=(c>>4)*32+(c&15)      (W1 -> even 16-col blocks)
//                          mode 2: f(c)=(c>>4)*32+16+(c&15)   (W2 -> odd 16-col blocks)
// outMatStride: per-expert element stride of the OUTPUT tensor.
__global__ void tconv_kernel(const float* __restrict__ in, bf16* __restrict__ out,
                             int R, int C, size_t outMatStride, int mode) {
    __shared__ float tile[32][33];
    const float* src = in + (size_t)R * C * blockIdx.z;
    bf16* dst = out + outMatStride * blockIdx.z;
    int c0 = blockIdx.x * 32, r0 = blockIdx.y * 32;
    int tx = threadIdx.x & 31, ty = threadIdx.x >> 5;  // ty 0..7
#pragma unroll
    for (int p = 0; p < 4; ++p)
        tile[ty + 8 * p][tx] = src[(size_t)(r0 + ty + 8 * p) * C + c0 + tx];
    __syncthreads();
#pragma unroll
    for (int p = 0; p < 2; ++p) {
        int w = threadIdx.x + 256 * p;
        int col = w >> 4;          // 0..31
        int pr  = w & 15;          // row pair
        int c = c0 + col;
        int dcol = (mode == 0) ? c : (((c >> 4) << 5) + ((mode == 2) ? 16 : 0) + (c & 15));
        bf16 lo = (bf16)tile[2 * pr][col];
        bf16 hi = (bf16)tile[2 * pr + 1][col];
        uint32_t pk = ((uint32_t)*(uint16_t*)&hi << 16) | *(uint16_t*)&lo;
        *(uint32_t*)(dst + (size_t)dcol * R + r0 + 2 * pr) = pk;
    }
}

// ---------------- GEMM stage 1: H = silu(X Wc_even) * (X Wc_odd), gathered rows ----
// Combined B: wc [E][4096][1024] bf16 (row = combined col, K contiguous).
// Double-buffered LDS, one barrier per K-step, counted-latency staging.
__global__ __launch_bounds__(256, 2)
void gemm1_kernel(const bf16* __restrict__ xb, const bf16* __restrict__ wc,
                  bf16* __restrict__ H, const int* __restrict__ ctrl,
                  const int* __restrict__ tokenId) {
    const int mt = blockIdx.x;
    if (mt >= ctrl[16]) return;
    const int e = ctrl[64 + mt];
    const int rowBase = ctrl[256 + mt];
    const int n0 = blockIdx.y * 128;   // combined-col tile base (0..4095)

    __shared__ char lds[65536];        // A: [0,32768) 2 bufs x 16KB; B: [32768,65536)

    const int tid = threadIdx.x, lane = tid & 63;
    const int wm = (tid >> 7) & 1, wn = (tid >> 6) & 1;

    const bf16* wb = wc + (size_t)e * 4096 * 1024;

    const bf16* aSrc[4]; const bf16* bSrc[4]; int dstOff[4];
#pragma unroll
    for (int rd = 0; rd < 4; ++rd) {
        int o = rd * 4096 + tid * 16;
        int r = o >> 7;                    // row 0..127
        int c2 = ((o >> 4) & 7) ^ (r & 7); // pre-swizzled source slot
        dstOff[rd] = o;
        int tok = tokenId[rowBase + r];
        aSrc[rd] = xb + (size_t)tok * D_MODEL + c2 * 8;
        bSrc[rd] = wb + (size_t)(n0 + r) * D_MODEL + c2 * 8;
    }

    f32x4 acc[4][4];
#pragma unroll
    for (int m = 0; m < 4; ++m)
#pragma unroll
        for (int n = 0; n < 4; ++n) acc[m][n] = (f32x4){0.f, 0.f, 0.f, 0.f};

    // prologue: stage K-tile 0 into buf0, wait, barrier
#pragma unroll
    for (int rd = 0; rd < 4; ++rd) {
        gload16(aSrc[rd], lds + dstOff[rd]);
        gload16(bSrc[rd], lds + 32768 + dstOff[rd]);
    }
    asm volatile("s_waitcnt vmcnt(0)" ::: "memory");
    asm volatile("s_barrier" ::: "memory");

    for (int kt = 0; kt < D_MODEL / 64; ++kt) {
        // stage next K-tile into the other buffer (overlaps with compute below)
        if (kt + 1 < D_MODEL / 64) {
            int bo = ((kt + 1) & 1) * 16384;
#pragma unroll
            for (int rd = 0; rd < 4; ++rd) {
                gload16(aSrc[rd] + (kt + 1) * 64, lds + bo + dstOff[rd]);
                gload16(bSrc[rd] + (kt + 1) * 64, lds + 32768 + bo + dstOff[rd]);
            }
        }
        const int bo = (kt & 1) * 16384;
#pragma unroll
        for (int ks = 0; ks < 2; ++ks) {
            bf16x8 af[4], bfr[4];
            int c2 = ks * 4 + (lane >> 4);
#pragma unroll
            for (int m = 0; m < 4; ++m) {
                int r = wm * 64 + m * 16 + (lane & 15);
                af[m] = *(const bf16x8*)(lds + bo + r * 128 + ((c2 ^ (r & 7)) << 4));
            }
#pragma unroll
            for (int n = 0; n < 4; ++n) {
                int r = wn * 64 + n * 16 + (lane & 15);
                bfr[n] = *(const bf16x8*)(lds + 32768 + bo + r * 128 + ((c2 ^ (r & 7)) << 4));
            }
#pragma unroll
            for (int m = 0; m < 4; ++m)
#pragma unroll
                for (int n = 0; n < 4; ++n)
                    acc[m][n] = __builtin_amdgcn_mfma_f32_16x16x32_bf16(af[m], bfr[n], acc[m][n], 0, 0, 0);
        }
        asm volatile("s_waitcnt vmcnt(0)" ::: "memory");
        asm volatile("s_barrier" ::: "memory");
    }

    // epilogue: n-frag pairs (0,1)=(g,v) and (2,3)=(g,v); H col = (n0>>1)+wn*32+(pair?16:0)+(lane&15)
#pragma unroll
    for (int m = 0; m < 4; ++m) {
#pragma unroll
        for (int j = 0; j < 4; ++j) {
            int rl = wm * 64 + m * 16 + (lane >> 4) * 4 + j;
            bf16* hb = H + (size_t)(rowBase + rl) * D_FF + (n0 >> 1) + wn * 32 + (lane & 15);
            {
                float g = acc[m][0][j], v = acc[m][1][j];
                hb[0] = (bf16)((g / (1.f + __expf(-g))) * v);
            }
            {
                float g = acc[m][2][j], v = acc[m][3][j];
                hb[16] = (bf16)((g / (1.f + __expf(-g))) * v);
            }
        }
    }
}

// ---------------- GEMM stage 2: O2[row] = w[row] * (H[row] @ W3) ----------------
__global__ __launch_bounds__(256, 2)
void gemm2_kernel(const bf16* __restrict__ H, const bf16* __restrict__ w3t,
                  bf16* __restrict__ O2, const int* __restrict__ ctrl,
                  const float* __restrict__ rowW) {
    const int mt = blockIdx.x;
    if (mt >= ctrl[16]) return;
    const int e = ctrl[64 + mt];
    const int rowBase = ctrl[256 + mt];
    const int n0 = blockIdx.y * 128;

    __shared__ char lds[65536];

    const int tid = threadIdx.x, lane = tid & 63;
    const int wm = (tid >> 7) & 1, wn = (tid >> 6) & 1;

    const bf16* w3b = w3t + (size_t)e * D_MODEL * D_FF;
    const bf16* aSrc[4]; const bf16* bSrc[4]; int dstOff[4];
#pragma unroll
    for (int rd = 0; rd < 4; ++rd) {
        int o = rd * 4096 + tid * 16;
        int r = o >> 7;
        int c2 = ((o >> 4) & 7) ^ (r & 7);
        dstOff[rd] = o;
        aSrc[rd] = H   + (size_t)(rowBase + r) * D_FF + c2 * 8;
        bSrc[rd] = w3b + (size_t)(n0 + r) * D_FF + c2 * 8;
    }

    f32x4 acc[4][4];
#pragma unroll
    for (int m = 0; m < 4; ++m)
#pragma unroll
        for (int n = 0; n < 4; ++n) acc[m][n] = (f32x4){0.f, 0.f, 0.f, 0.f};

#pragma unroll
    for (int rd = 0; rd < 4; ++rd) {
        gload16(aSrc[rd], lds + dstOff[rd]);
        gload16(bSrc[rd], lds + 32768 + dstOff[rd]);
    }
    asm volatile("s_waitcnt vmcnt(0)" ::: "memory");
    asm volatile("s_barrier" ::: "memory");

    for (int kt = 0; kt < D_FF / 64; ++kt) {
        if (kt + 1 < D_FF / 64) {
            int bo = ((kt + 1) & 1) * 16384;
#pragma unroll
            for (int rd = 0; rd < 4; ++rd) {
                gload16(aSrc[rd] + (kt + 1) * 64, lds + bo + dstOff[rd]);
                gload16(bSrc[rd] + (kt + 1) * 64, lds + 32768 + bo + dstOff[rd]);
            }
        }
        const int bo = (kt & 1) * 16384;
#pragma unroll
        for (int ks = 0; ks < 2; ++ks) {
            bf16x8 af[4], bfr[4];
            int c2 = ks * 4 + (lane >> 4);
#pragma unroll
            for (int m = 0; m < 4; ++m) {
                int r = wm * 64 + m * 16 + (lane & 15);
                af[m] = *(const bf16x8*)(lds + bo + r * 128 + ((c2 ^ (r & 7)) << 4));
            }
#pragma unroll
            for (int n = 0; n < 4; ++n) {
                int r = wn * 64 + n * 16 + (lane & 15);
                bfr[n] = *(const bf16x8*)(lds + 32768 + bo + r * 128 + ((c2 ^ (r & 7)) << 4));
            }
#pragma unroll
            for (int m = 0; m < 4; ++m)
#pragma unroll
                for (int n = 0; n < 4; ++n)
                    acc[m][n] = __builtin_amdgcn_mfma_f32_16x16x32_bf16(af[m], bfr[n], acc[m][n], 0, 0, 0);
        }
        asm volatile("s_waitcnt vmcnt(0)" ::: "memory");
        asm volatile("s_barrier" ::: "memory");
    }

#pragma unroll
    for (int m = 0; m < 4; ++m) {
#pragma unroll
        for (int j = 0; j < 4; ++j) {
            int rl = wm * 64 + m * 16 + (lane >> 4) * 4 + j;
            int row = rowBase + rl;
            float wgt = rowW[row];
            bf16* obase = O2 + (size_t)row * D_MODEL + n0 + wn * 64 + (lane & 15);
#pragma unroll
            for (int n = 0; n < 4; ++n)
                obase[n * 16] = (bf16)(wgt * acc[m][n][j]);
        }
    }
}

// ---------------- combine: out[t] = O2[rowOf[t,0]] + O2[rowOf[t,1]] ----------------
__global__ void combine_kernel(const bf16* __restrict__ O2, const int* __restrict__ rowOf,
                               float* __restrict__ out) {
    int t = blockIdx.x;
    int r0 = rowOf[t * 2 + 0], r1 = rowOf[t * 2 + 1];
    int c = threadIdx.x * 4;
    bf16x4 a = *(const bf16x4*)(O2 + (size_t)r0 * D_MODEL + c);
    bf16x4 b = *(const bf16x4*)(O2 + (size_t)r1 * D_MODEL + c);
    float4 o;
    o.x = (float)a[0] + (float)b[0];
    o.y = (float)a[1] + (float)b[1];
    o.z = (float)a[2] + (float)b[2];
    o.w = (float)a[3] + (float)b[3];
    *(float4*)(out + (size_t)t * D_MODEL + c) = o;
}

// ---------------- launch ----------------
extern "C" void kernel_launch(void* const* d_in, const int* in_sizes, int n_in,
                              void* d_out, int out_size, void* d_ws, size_t ws_size,
                              hipStream_t stream) {
    const float* x  = (const float*)d_in[0];
    const int*   ei = (const int*)d_in[1];
    const float* ew = (const float*)d_in[2];
    const float* w1 = (const float*)d_in[3];
    const float* w2 = (const float*)d_in[4];
    const float* w3 = (const float*)d_in[5];
    float* out = (float*)d_out;

    char* w = (char*)d_ws;
    constexpr size_t CTRL_OFF  = 0;
    constexpr size_t TOK_OFF   = 4096;
    constexpr size_t ROWW_OFF  = TOK_OFF + (size_t)MAX_ROWS * 4;       // 73728
    constexpr size_t ROWOF_OFF = ROWW_OFF + (size_t)MAX_ROWS * 4;      // 143360
    constexpr size_t XB_OFF    = ROWOF_OFF + (size_t)T_TOKENS * 2 * 4; // 274432
    constexpr size_t WC_OFF    = XB_OFF + (size_t)T_TOKENS * D_MODEL * 2;       // 16 MB later
    constexpr size_t W3T_OFF   = WC_OFF + (size_t)N_EXP * 4096 * 1024 * 2;      // +64 MB
    constexpr size_t H_OFF     = W3T_OFF + (size_t)N_EXP * D_MODEL * D_FF * 2;  // +32 MB
    // O2 (bf16, MAX_ROWS x D_MODEL = 35.7 MB) aliases wc (64 MB), dead after gemm1.
    constexpr size_t O2_OFF    = WC_OFF;

    int*   ctrl    = (int*)(w + CTRL_OFF);
    int*   tokenId = (int*)(w + TOK_OFF);
    float* rowW    = (float*)(w + ROWW_OFF);
    int*   rowOf   = (int*)(w + ROWOF_OFF);
    bf16*  xb      = (bf16*)(w + XB_OFF);
    bf16*  wc      = (bf16*)(w + WC_OFF);
    bf16*  w3t     = (bf16*)(w + W3T_OFF);
    bf16*  H       = (bf16*)(w + H_OFF);
    bf16*  O2      = (bf16*)(w + O2_OFF);

    hipMemsetAsync(ctrl, 0, 64, stream);  // counts + cursors

    count_kernel<<<T_TOKENS / 256, 256, 0, stream>>>(ei, ctrl);
    scan_kernel<<<1, 256, 0, stream>>>(ctrl, tokenId, rowW);
    scatter_kernel<<<T_TOKENS / 256, 256, 0, stream>>>(ei, ew, ctrl, tokenId, rowW, rowOf);

    cvtx_kernel<<<(T_TOKENS * D_MODEL) / (256 * 8), 256, 0, stream>>>(x, xb);
    // W1 -> even 16-col blocks of wc, W2 -> odd; W3 -> plain transposed.
    // outMatStride: wc is [E][4096][1024]; w3t is [E][1024][2048].
    tconv_kernel<<<dim3(D_FF / 32, D_MODEL / 32, N_EXP), 256, 0, stream>>>(w1, wc, D_MODEL, D_FF, (size_t)4096 * 1024, 1);
    tconv_kernel<<<dim3(D_FF / 32, D_MODEL / 32, N_EXP), 256, 0, stream>>>(w2, wc, D_MODEL, D_FF, (size_t)4096 * 1024, 2);
    tconv_kernel<<<dim3(D_MODEL / 32, D_FF / 32, N_EXP), 256, 0, stream>>>(w3, w3t, D_FF, D_MODEL, (size_t)D_FF * D_MODEL, 0);

    gemm1_kernel<<<dim3(MAX_MT, 4096 / 128), 256, 0, stream>>>(xb, wc, H, ctrl, tokenId);
    gemm2_kernel<<<dim3(MAX_MT, D_MODEL / 128), 256, 0, stream>>>(H, w3t, O2, ctrl, rowW);
    combine_kernel<<<T_TOKENS, 256, 0, stream>>>(O2, rowOf, out);
}

// Round 6
// 405.608 us; speedup vs baseline: 1.2340x; 1.0279x over previous
//
#include <hip/hip_runtime.h>
#include <hip/hip_bf16.h>
#include <cstdint>
#include <cstddef>

typedef __bf16 bf16;
typedef __attribute__((ext_vector_type(4))) float f32x4;
typedef __attribute__((ext_vector_type(8))) __bf16 bf16x8;
typedef __attribute__((ext_vector_type(4))) __bf16 bf16x4;

// ---------------- constants ----------------
#define T_TOKENS 8192
#define D_MODEL  1024
#define D_FF     2048
#define N_EXP    8
#define MAX_ROWS 17408   // 16384 + 8*128 padding
#define MAX_MT   136     // max m-tiles of 128 (8 XCD chunks of 17)

// ctrl layout (int indices): counts[0..7], cursors[8..15], numTiles[16],
// pstart[32..40], tileExpert[64..199], tileRow[256..391]

__device__ __forceinline__ void gload16(const void* g, void* l) {
    __builtin_amdgcn_global_load_lds((const __attribute__((address_space(1))) void*)g,
                                     (__attribute__((address_space(3))) void*)l, 16, 0, 0);
}

// ---------------- dispatch building ----------------
__global__ void count_kernel(const int* __restrict__ ei, int* __restrict__ ctrl) {
    __shared__ int lc[N_EXP];
    if (threadIdx.x < N_EXP) lc[threadIdx.x] = 0;
    __syncthreads();
    int t = blockIdx.x * blockDim.x + threadIdx.x;
    if (t < T_TOKENS) {
        atomicAdd(&lc[ei[t * 2 + 0]], 1);
        atomicAdd(&lc[ei[t * 2 + 1]], 1);
    }
    __syncthreads();
    if (threadIdx.x < N_EXP) atomicAdd(&ctrl[threadIdx.x], lc[threadIdx.x]);
}

__global__ void scan_kernel(int* __restrict__ ctrl, int* __restrict__ tokenId,
                            float* __restrict__ rowW) {
    if (threadIdx.x == 0) {
        int s = 0, nt = 0;
        for (int e = 0; e < N_EXP; ++e) {
            ctrl[32 + e] = s;
            int cnt = ctrl[e];
            int tiles = (cnt + 127) >> 7;
            for (int i = 0; i < tiles; ++i) { ctrl[64 + nt] = e; ctrl[256 + nt] = s + (i << 7); ++nt; }
            s += tiles << 7;
        }
        ctrl[32 + 8] = s;
        ctrl[16] = nt;
    }
    for (int r = threadIdx.x; r < MAX_ROWS; r += blockDim.x) { tokenId[r] = 0; rowW[r] = 0.f; }
}

__global__ void scatter_kernel(const int* __restrict__ ei, const float* __restrict__ ew,
                               int* __restrict__ ctrl, int* __restrict__ tokenId,
                               float* __restrict__ rowW, int* __restrict__ rowOf) {
    int t = blockIdx.x * blockDim.x + threadIdx.x;
    if (t >= T_TOKENS) return;
    for (int k = 0; k < 2; ++k) {
        int e = ei[t * 2 + k];
        int pos = atomicAdd(&ctrl[8 + e], 1);
        int r = ctrl[32 + e] + pos;
        tokenId[r] = t;
        rowW[r] = ew[t * 2 + k];
        rowOf[t * 2 + k] = r;
    }
}

// ---------------- conversions ----------------
__global__ void cvtx_kernel(const float* __restrict__ x, bf16* __restrict__ xb) {
    int i = (blockIdx.x * 256 + threadIdx.x) * 8;
    float4 v0 = *(const float4*)(x + i);
    float4 v1 = *(const float4*)(x + i + 4);
    bf16x8 o;
    o[0] = (bf16)v0.x; o[1] = (bf16)v0.y; o[2] = (bf16)v0.z; o[3] = (bf16)v0.w;
    o[4] = (bf16)v1.x; o[5] = (bf16)v1.y; o[6] = (bf16)v1.z; o[7] = (bf16)v1.w;
    *(bf16x8*)(xb + i) = o;
}

// transpose-convert: in fp32 [E][R][C] -> out bf16 [E][f(C)][R]
// mode 0: f(c)=c (plain). mode 1: f(c)=(c>>4)*32+(c&15)      (W1 -> even 16-col blocks)
//                          mode 2: f(c)=(c>>4)*32+16+(c&15)   (W2 -> odd 16-col blocks)
// outMatStride: per-expert element stride of the OUTPUT tensor.
__global__ void tconv_kernel(const float* __restrict__ in, bf16* __restrict__ out,
                             int R, int C, size_t outMatStride, int mode) {
    __shared__ float tile[32][33];
    const float* src = in + (size_t)R * C * blockIdx.z;
    bf16* dst = out + outMatStride * blockIdx.z;
    int c0 = blockIdx.x * 32, r0 = blockIdx.y * 32;
    int tx = threadIdx.x & 31, ty = threadIdx.x >> 5;  // ty 0..7
#pragma unroll
    for (int p = 0; p < 4; ++p)
        tile[ty + 8 * p][tx] = src[(size_t)(r0 + ty + 8 * p) * C + c0 + tx];
    __syncthreads();
#pragma unroll
    for (int p = 0; p < 2; ++p) {
        int w = threadIdx.x + 256 * p;
        int col = w >> 4;          // 0..31
        int pr  = w & 15;          // row pair
        int c = c0 + col;
        int dcol = (mode == 0) ? c : (((c >> 4) << 5) + ((mode == 2) ? 16 : 0) + (c & 15));
        bf16 lo = (bf16)tile[2 * pr][col];
        bf16 hi = (bf16)tile[2 * pr + 1][col];
        uint32_t pk = ((uint32_t)*(uint16_t*)&hi << 16) | *(uint16_t*)&lo;
        *(uint32_t*)(dst + (size_t)dcol * R + r0 + 2 * pr) = pk;
    }
}

// ---------------- GEMM stage 1: H = silu(X Wc_even) * (X Wc_odd), gathered rows ----
// Combined B: wc [E][4096][1024] bf16 (row = combined col, K contiguous).
// Double-buffered LDS, one barrier per K-step.
// Grid: 1D 4352 blocks. XCD-locality swizzle: xcd = L&7 owns m-tiles
// [xcd*17, xcd*17+17); m-minor within chunk so the 17 concurrent same-XCD
// blocks share each B n-slice (fetched once per XCD) and the 4.3 MB A-chunk
// stays ~L2-resident across the n-sweep.
__global__ __launch_bounds__(256, 2)
void gemm1_kernel(const bf16* __restrict__ xb, const bf16* __restrict__ wc,
                  bf16* __restrict__ H, const int* __restrict__ ctrl,
                  const int* __restrict__ tokenId) {
    const int L = blockIdx.x;
    const int xcd = L & 7;
    const int w = L >> 3;                 // 0..543
    const int mt = xcd * 17 + (w % 17);   // 0..135
    const int n0 = (w / 17) * 128;        // combined-col tile base (0..4095)
    if (mt >= ctrl[16]) return;
    const int e = ctrl[64 + mt];
    const int rowBase = ctrl[256 + mt];

    __shared__ char lds[65536];        // A: [0,32768) 2 bufs x 16KB; B: [32768,65536)

    const int tid = threadIdx.x, lane = tid & 63;
    const int wm = (tid >> 7) & 1, wn = (tid >> 6) & 1;

    const bf16* wb = wc + (size_t)e * 4096 * 1024;

    const bf16* aSrc[4]; const bf16* bSrc[4]; int dstOff[4];
#pragma unroll
    for (int rd = 0; rd < 4; ++rd) {
        int o = rd * 4096 + tid * 16;
        int r = o >> 7;                    // row 0..127
        int c2 = ((o >> 4) & 7) ^ (r & 7); // pre-swizzled source slot
        dstOff[rd] = o;
        int tok = tokenId[rowBase + r];
        aSrc[rd] = xb + (size_t)tok * D_MODEL + c2 * 8;
        bSrc[rd] = wb + (size_t)(n0 + r) * D_MODEL + c2 * 8;
    }

    f32x4 acc[4][4];
#pragma unroll
    for (int m = 0; m < 4; ++m)
#pragma unroll
        for (int n = 0; n < 4; ++n) acc[m][n] = (f32x4){0.f, 0.f, 0.f, 0.f};

    // prologue: stage K-tile 0 into buf0, wait, barrier
#pragma unroll
    for (int rd = 0; rd < 4; ++rd) {
        gload16(aSrc[rd], lds + dstOff[rd]);
        gload16(bSrc[rd], lds + 32768 + dstOff[rd]);
    }
    asm volatile("s_waitcnt vmcnt(0)" ::: "memory");
    asm volatile("s_barrier" ::: "memory");

    for (int kt = 0; kt < D_MODEL / 64; ++kt) {
        // stage next K-tile into the other buffer (overlaps with compute below)
        if (kt + 1 < D_MODEL / 64) {
            int bo = ((kt + 1) & 1) * 16384;
#pragma unroll
            for (int rd = 0; rd < 4; ++rd) {
                gload16(aSrc[rd] + (kt + 1) * 64, lds + bo + dstOff[rd]);
                gload16(bSrc[rd] + (kt + 1) * 64, lds + 32768 + bo + dstOff[rd]);
            }
        }
        const int bo = (kt & 1) * 16384;
#pragma unroll
        for (int ks = 0; ks < 2; ++ks) {
            bf16x8 af[4], bfr[4];
            int c2 = ks * 4 + (lane >> 4);
#pragma unroll
            for (int m = 0; m < 4; ++m) {
                int r = wm * 64 + m * 16 + (lane & 15);
                af[m] = *(const bf16x8*)(lds + bo + r * 128 + ((c2 ^ (r & 7)) << 4));
            }
#pragma unroll
            for (int n = 0; n < 4; ++n) {
                int r = wn * 64 + n * 16 + (lane & 15);
                bfr[n] = *(const bf16x8*)(lds + 32768 + bo + r * 128 + ((c2 ^ (r & 7)) << 4));
            }
#pragma unroll
            for (int m = 0; m < 4; ++m)
#pragma unroll
                for (int n = 0; n < 4; ++n)
                    acc[m][n] = __builtin_amdgcn_mfma_f32_16x16x32_bf16(af[m], bfr[n], acc[m][n], 0, 0, 0);
        }
        asm volatile("s_waitcnt vmcnt(0)" ::: "memory");
        asm volatile("s_barrier" ::: "memory");
    }

    // epilogue: n-frag pairs (0,1)=(g,v) and (2,3)=(g,v); H col = (n0>>1)+wn*32+(pair?16:0)+(lane&15)
#pragma unroll
    for (int m = 0; m < 4; ++m) {
#pragma unroll
        for (int j = 0; j < 4; ++j) {
            int rl = wm * 64 + m * 16 + (lane >> 4) * 4 + j;
            bf16* hb = H + (size_t)(rowBase + rl) * D_FF + (n0 >> 1) + wn * 32 + (lane & 15);
            {
                float g = acc[m][0][j], v = acc[m][1][j];
                hb[0] = (bf16)((g / (1.f + __expf(-g))) * v);
            }
            {
                float g = acc[m][2][j], v = acc[m][3][j];
                hb[16] = (bf16)((g / (1.f + __expf(-g))) * v);
            }
        }
    }
}

// ---------------- GEMM stage 2: O2[row] = w[row] * (H[row] @ W3) ----------------
// Grid: 1D 1088 blocks. XCD swizzle, n-minor within chunk: the 8 blocks
// sharing one A-tile (H rows) run concurrently on one XCD (A fetched once);
// B_e (4 MB) ~L2-resident per XCD.
__global__ __launch_bounds__(256, 2)
void gemm2_kernel(const bf16* __restrict__ H, const bf16* __restrict__ w3t,
                  bf16* __restrict__ O2, const int* __restrict__ ctrl,
                  const float* __restrict__ rowW) {
    const int L = blockIdx.x;
    const int xcd = L & 7;
    const int w = L >> 3;                 // 0..135
    const int n0 = (w & 7) * 128;
    const int mt = xcd * 17 + (w >> 3);   // 0..135
    if (mt >= ctrl[16]) return;
    const int e = ctrl[64 + mt];
    const int rowBase = ctrl[256 + mt];

    __shared__ char lds[65536];

    const int tid = threadIdx.x, lane = tid & 63;
    const int wm = (tid >> 7) & 1, wn = (tid >> 6) & 1;

    const bf16* w3b = w3t + (size_t)e * D_MODEL * D_FF;
    const bf16* aSrc[4]; const bf16* bSrc[4]; int dstOff[4];
#pragma unroll
    for (int rd = 0; rd < 4; ++rd) {
        int o = rd * 4096 + tid * 16;
        int r = o >> 7;
        int c2 = ((o >> 4) & 7) ^ (r & 7);
        dstOff[rd] = o;
        aSrc[rd] = H   + (size_t)(rowBase + r) * D_FF + c2 * 8;
        bSrc[rd] = w3b + (size_t)(n0 + r) * D_FF + c2 * 8;
    }

    f32x4 acc[4][4];
#pragma unroll
    for (int m = 0; m < 4; ++m)
#pragma unroll
        for (int n = 0; n < 4; ++n) acc[m][n] = (f32x4){0.f, 0.f, 0.f, 0.f};

#pragma unroll
    for (int rd = 0; rd < 4; ++rd) {
        gload16(aSrc[rd], lds + dstOff[rd]);
        gload16(bSrc[rd], lds + 32768 + dstOff[rd]);
    }
    asm volatile("s_waitcnt vmcnt(0)" ::: "memory");
    asm volatile("s_barrier" ::: "memory");

    for (int kt = 0; kt < D_FF / 64; ++kt) {
        if (kt + 1 < D_FF / 64) {
            int bo = ((kt + 1) & 1) * 16384;
#pragma unroll
            for (int rd = 0; rd < 4; ++rd) {
                gload16(aSrc[rd] + (kt + 1) * 64, lds + bo + dstOff[rd]);
                gload16(bSrc[rd] + (kt + 1) * 64, lds + 32768 + bo + dstOff[rd]);
            }
        }
        const int bo = (kt & 1) * 16384;
#pragma unroll
        for (int ks = 0; ks < 2; ++ks) {
            bf16x8 af[4], bfr[4];
            int c2 = ks * 4 + (lane >> 4);
#pragma unroll
            for (int m = 0; m < 4; ++m) {
                int r = wm * 64 + m * 16 + (lane & 15);
                af[m] = *(const bf16x8*)(lds + bo + r * 128 + ((c2 ^ (r & 7)) << 4));
            }
#pragma unroll
            for (int n = 0; n < 4; ++n) {
                int r = wn * 64 + n * 16 + (lane & 15);
                bfr[n] = *(const bf16x8*)(lds + 32768 + bo + r * 128 + ((c2 ^ (r & 7)) << 4));
            }
#pragma unroll
            for (int m = 0; m < 4; ++m)
#pragma unroll
                for (int n = 0; n < 4; ++n)
                    acc[m][n] = __builtin_amdgcn_mfma_f32_16x16x32_bf16(af[m], bfr[n], acc[m][n], 0, 0, 0);
        }
        asm volatile("s_waitcnt vmcnt(0)" ::: "memory");
        asm volatile("s_barrier" ::: "memory");
    }

#pragma unroll
    for (int m = 0; m < 4; ++m) {
#pragma unroll
        for (int j = 0; j < 4; ++j) {
            int rl = wm * 64 + m * 16 + (lane >> 4) * 4 + j;
            int row = rowBase + rl;
            float wgt = rowW[row];
            bf16* obase = O2 + (size_t)row * D_MODEL + n0 + wn * 64 + (lane & 15);
#pragma unroll
            for (int n = 0; n < 4; ++n)
                obase[n * 16] = (bf16)(wgt * acc[m][n][j]);
        }
    }
}

// ---------------- combine: out[t] = O2[rowOf[t,0]] + O2[rowOf[t,1]] ----------------
__global__ void combine_kernel(const bf16* __restrict__ O2, const int* __restrict__ rowOf,
                               float* __restrict__ out) {
    int t = blockIdx.x;
    int r0 = rowOf[t * 2 + 0], r1 = rowOf[t * 2 + 1];
    int c = threadIdx.x * 4;
    bf16x4 a = *(const bf16x4*)(O2 + (size_t)r0 * D_MODEL + c);
    bf16x4 b = *(const bf16x4*)(O2 + (size_t)r1 * D_MODEL + c);
    float4 o;
    o.x = (float)a[0] + (float)b[0];
    o.y = (float)a[1] + (float)b[1];
    o.z = (float)a[2] + (float)b[2];
    o.w = (float)a[3] + (float)b[3];
    *(float4*)(out + (size_t)t * D_MODEL + c) = o;
}

// ---------------- launch ----------------
extern "C" void kernel_launch(void* const* d_in, const int* in_sizes, int n_in,
                              void* d_out, int out_size, void* d_ws, size_t ws_size,
                              hipStream_t stream) {
    const float* x  = (const float*)d_in[0];
    const int*   ei = (const int*)d_in[1];
    const float* ew = (const float*)d_in[2];
    const float* w1 = (const float*)d_in[3];
    const float* w2 = (const float*)d_in[4];
    const float* w3 = (const float*)d_in[5];
    float* out = (float*)d_out;

    char* w = (char*)d_ws;
    constexpr size_t CTRL_OFF  = 0;
    constexpr size_t TOK_OFF   = 4096;
    constexpr size_t ROWW_OFF  = TOK_OFF + (size_t)MAX_ROWS * 4;       // 73728
    constexpr size_t ROWOF_OFF = ROWW_OFF + (size_t)MAX_ROWS * 4;      // 143360
    constexpr size_t XB_OFF    = ROWOF_OFF + (size_t)T_TOKENS * 2 * 4; // 274432
    constexpr size_t WC_OFF    = XB_OFF + (size_t)T_TOKENS * D_MODEL * 2;       // 16 MB later
    constexpr size_t W3T_OFF   = WC_OFF + (size_t)N_EXP * 4096 * 1024 * 2;      // +64 MB
    constexpr size_t H_OFF     = W3T_OFF + (size_t)N_EXP * D_MODEL * D_FF * 2;  // +32 MB
    // O2 (bf16, MAX_ROWS x D_MODEL = 35.7 MB) aliases wc (64 MB), dead after gemm1.
    constexpr size_t O2_OFF    = WC_OFF;

    int*   ctrl    = (int*)(w + CTRL_OFF);
    int*   tokenId = (int*)(w + TOK_OFF);
    float* rowW    = (float*)(w + ROWW_OFF);
    int*   rowOf   = (int*)(w + ROWOF_OFF);
    bf16*  xb      = (bf16*)(w + XB_OFF);
    bf16*  wc      = (bf16*)(w + WC_OFF);
    bf16*  w3t     = (bf16*)(w + W3T_OFF);
    bf16*  H       = (bf16*)(w + H_OFF);
    bf16*  O2      = (bf16*)(w + O2_OFF);

    hipMemsetAsync(ctrl, 0, 64, stream);  // counts + cursors

    count_kernel<<<T_TOKENS / 256, 256, 0, stream>>>(ei, ctrl);
    scan_kernel<<<1, 256, 0, stream>>>(ctrl, tokenId, rowW);
    scatter_kernel<<<T_TOKENS / 256, 256, 0, stream>>>(ei, ew, ctrl, tokenId, rowW, rowOf);

    cvtx_kernel<<<(T_TOKENS * D_MODEL) / (256 * 8), 256, 0, stream>>>(x, xb);
    // W1 -> even 16-col blocks of wc, W2 -> odd; W3 -> plain transposed.
    // outMatStride: wc is [E][4096][1024]; w3t is [E][1024][2048].
    tconv_kernel<<<dim3(D_FF / 32, D_MODEL / 32, N_EXP), 256, 0, stream>>>(w1, wc, D_MODEL, D_FF, (size_t)4096 * 1024, 1);
    tconv_kernel<<<dim3(D_FF / 32, D_MODEL / 32, N_EXP), 256, 0, stream>>>(w2, wc, D_MODEL, D_FF, (size_t)4096 * 1024, 2);
    tconv_kernel<<<dim3(D_MODEL / 32, D_FF / 32, N_EXP), 256, 0, stream>>>(w3, w3t, D_FF, D_MODEL, (size_t)D_FF * D_MODEL, 0);

    gemm1_kernel<<<MAX_MT * (4096 / 128), 256, 0, stream>>>(xb, wc, H, ctrl, tokenId);
    gemm2_kernel<<<MAX_MT * (D_MODEL / 128), 256, 0, stream>>>(H, w3t, O2, ctrl, rowW);
    combine_kernel<<<T_TOKENS, 256, 0, stream>>>(O2, rowOf, out);
}

// Round 7
// 389.915 us; speedup vs baseline: 1.2837x; 1.0402x over previous
//
#include <hip/hip_runtime.h>
#include <hip/hip_bf16.h>
#include <cstdint>
#include <cstddef>

typedef __bf16 bf16;
typedef __attribute__((ext_vector_type(4))) float f32x4;
typedef __attribute__((ext_vector_type(8))) __bf16 bf16x8;
typedef __attribute__((ext_vector_type(4))) __bf16 bf16x4;

// ---------------- constants ----------------
#define T_TOKENS 8192
#define D_MODEL  1024
#define D_FF     2048
#define N_EXP    8
#define MAX_ROWS 17408   // 16384 + 8*128 padding
#define MAX_MT   136     // max m-tiles of 128 (8 XCD chunks of 17)

// ctrl layout (int indices): counts[0..7], cursors[8..15], numTiles[16],
// pstart[32..40], tileExpert[64..199], tileRow[256..391]

__device__ __forceinline__ void gload16(const void* g, void* l) {
    __builtin_amdgcn_global_load_lds((const __attribute__((address_space(1))) void*)g,
                                     (__attribute__((address_space(3))) void*)l, 16, 0, 0);
}

// ---------------- dispatch building ----------------
__global__ void count_kernel(const int* __restrict__ ei, int* __restrict__ ctrl) {
    __shared__ int lc[N_EXP];
    if (threadIdx.x < N_EXP) lc[threadIdx.x] = 0;
    __syncthreads();
    int t = blockIdx.x * blockDim.x + threadIdx.x;
    if (t < T_TOKENS) {
        atomicAdd(&lc[ei[t * 2 + 0]], 1);
        atomicAdd(&lc[ei[t * 2 + 1]], 1);
    }
    __syncthreads();
    if (threadIdx.x < N_EXP) atomicAdd(&ctrl[threadIdx.x], lc[threadIdx.x]);
}

__global__ void scan_kernel(int* __restrict__ ctrl, int* __restrict__ tokenId,
                            float* __restrict__ rowW) {
    if (threadIdx.x == 0) {
        int s = 0, nt = 0;
        for (int e = 0; e < N_EXP; ++e) {
            ctrl[32 + e] = s;
            int cnt = ctrl[e];
            int tiles = (cnt + 127) >> 7;
            for (int i = 0; i < tiles; ++i) { ctrl[64 + nt] = e; ctrl[256 + nt] = s + (i << 7); ++nt; }
            s += tiles << 7;
        }
        ctrl[32 + 8] = s;
        ctrl[16] = nt;
    }
    for (int r = threadIdx.x; r < MAX_ROWS; r += blockDim.x) { tokenId[r] = 0; rowW[r] = 0.f; }
}

__global__ void scatter_kernel(const int* __restrict__ ei, const float* __restrict__ ew,
                               int* __restrict__ ctrl, int* __restrict__ tokenId,
                               float* __restrict__ rowW, int* __restrict__ rowOf) {
    int t = blockIdx.x * blockDim.x + threadIdx.x;
    if (t >= T_TOKENS) return;
    for (int k = 0; k < 2; ++k) {
        int e = ei[t * 2 + k];
        int pos = atomicAdd(&ctrl[8 + e], 1);
        int r = ctrl[32 + e] + pos;
        tokenId[r] = t;
        rowW[r] = ew[t * 2 + k];
        rowOf[t * 2 + k] = r;
    }
}

// ---------------- conversions ----------------
__global__ void cvtx_kernel(const float* __restrict__ x, bf16* __restrict__ xb) {
    int i = (blockIdx.x * 256 + threadIdx.x) * 8;
    float4 v0 = *(const float4*)(x + i);
    float4 v1 = *(const float4*)(x + i + 4);
    bf16x8 o;
    o[0] = (bf16)v0.x; o[1] = (bf16)v0.y; o[2] = (bf16)v0.z; o[3] = (bf16)v0.w;
    o[4] = (bf16)v1.x; o[5] = (bf16)v1.y; o[6] = (bf16)v1.z; o[7] = (bf16)v1.w;
    *(bf16x8*)(xb + i) = o;
}

// transpose-convert: in fp32 [E][R][C] -> out bf16 [E][f(C)][R]
// mode 0: f(c)=c (plain). mode 1: f(c)=(c>>4)*32+(c&15)      (W1 -> even 16-col blocks)
//                          mode 2: f(c)=(c>>4)*32+16+(c&15)   (W2 -> odd 16-col blocks)
// outMatStride: per-expert element stride of the OUTPUT tensor.
__global__ void tconv_kernel(const float* __restrict__ in, bf16* __restrict__ out,
                             int R, int C, size_t outMatStride, int mode) {
    __shared__ float tile[32][33];
    const float* src = in + (size_t)R * C * blockIdx.z;
    bf16* dst = out + outMatStride * blockIdx.z;
    int c0 = blockIdx.x * 32, r0 = blockIdx.y * 32;
    int tx = threadIdx.x & 31, ty = threadIdx.x >> 5;  // ty 0..7
#pragma unroll
    for (int p = 0; p < 4; ++p)
        tile[ty + 8 * p][tx] = src[(size_t)(r0 + ty + 8 * p) * C + c0 + tx];
    __syncthreads();
#pragma unroll
    for (int p = 0; p < 2; ++p) {
        int w = threadIdx.x + 256 * p;
        int col = w >> 4;          // 0..31
        int pr  = w & 15;          // row pair
        int c = c0 + col;
        int dcol = (mode == 0) ? c : (((c >> 4) << 5) + ((mode == 2) ? 16 : 0) + (c & 15));
        bf16 lo = (bf16)tile[2 * pr][col];
        bf16 hi = (bf16)tile[2 * pr + 1][col];
        uint32_t pk = ((uint32_t)*(uint16_t*)&hi << 16) | *(uint16_t*)&lo;
        *(uint32_t*)(dst + (size_t)dcol * R + r0 + 2 * pr) = pk;
    }
}

// ---------------- GEMM stage 1: H = silu(X Wc_even) * (X Wc_odd), gathered rows ----
// Combined B: wc [E][4096][1024] bf16 (row = combined col, K contiguous).
// m97-style 2-barrier single-buffer loop (measured-best at 128^2: 3 blocks/CU
// co-scheduling hides the staging drain better than explicit double-buffer).
// Grid: 1D 4352 blocks, XCD-locality swizzle (xcd = L&7 owns m-tiles chunk).
__global__ __launch_bounds__(256, 3)
void gemm1_kernel(const bf16* __restrict__ xb, const bf16* __restrict__ wc,
                  bf16* __restrict__ H, const int* __restrict__ ctrl,
                  const int* __restrict__ tokenId) {
    const int L = blockIdx.x;
    const int xcd = L & 7;
    const int w = L >> 3;                 // 0..543
    const int mt = xcd * 17 + (w % 17);   // 0..135
    const int n0 = (w / 17) * 128;        // combined-col tile base (0..4095)
    if (mt >= ctrl[16]) return;
    const int e = ctrl[64 + mt];
    const int rowBase = ctrl[256 + mt];

    __shared__ char lds[32768];        // A: [0,16384)  B: [16384,32768)

    const int tid = threadIdx.x, lane = tid & 63;
    const int wm = (tid >> 7) & 1, wn = (tid >> 6) & 1;

    const bf16* wb = wc + (size_t)e * 4096 * 1024;

    const bf16* aSrc[4]; const bf16* bSrc[4]; int dstOff[4];
#pragma unroll
    for (int rd = 0; rd < 4; ++rd) {
        int o = rd * 4096 + tid * 16;
        int r = o >> 7;                    // row 0..127
        int c2 = ((o >> 4) & 7) ^ (r & 7); // pre-swizzled source slot
        dstOff[rd] = o;
        int tok = tokenId[rowBase + r];
        aSrc[rd] = xb + (size_t)tok * D_MODEL + c2 * 8;
        bSrc[rd] = wb + (size_t)(n0 + r) * D_MODEL + c2 * 8;
    }

    f32x4 acc[4][4];
#pragma unroll
    for (int m = 0; m < 4; ++m)
#pragma unroll
        for (int n = 0; n < 4; ++n) acc[m][n] = (f32x4){0.f, 0.f, 0.f, 0.f};

    for (int kt = 0; kt < D_MODEL / 64; ++kt) {
#pragma unroll
        for (int rd = 0; rd < 4; ++rd) {
            gload16(aSrc[rd] + kt * 64, lds + dstOff[rd]);
            gload16(bSrc[rd] + kt * 64, lds + 16384 + dstOff[rd]);
        }
        __syncthreads();   // drains vmcnt before any wave reads
#pragma unroll
        for (int ks = 0; ks < 2; ++ks) {
            bf16x8 af[4], bfr[4];
            int c2 = ks * 4 + (lane >> 4);
#pragma unroll
            for (int m = 0; m < 4; ++m) {
                int r = wm * 64 + m * 16 + (lane & 15);
                af[m] = *(const bf16x8*)(lds + r * 128 + ((c2 ^ (r & 7)) << 4));
            }
#pragma unroll
            for (int n = 0; n < 4; ++n) {
                int r = wn * 64 + n * 16 + (lane & 15);
                bfr[n] = *(const bf16x8*)(lds + 16384 + r * 128 + ((c2 ^ (r & 7)) << 4));
            }
#pragma unroll
            for (int m = 0; m < 4; ++m)
#pragma unroll
                for (int n = 0; n < 4; ++n)
                    acc[m][n] = __builtin_amdgcn_mfma_f32_16x16x32_bf16(af[m], bfr[n], acc[m][n], 0, 0, 0);
        }
        __syncthreads();   // all waves done reading before next stage overwrites
    }

    // epilogue: n-frag pairs (0,1)=(g,v) and (2,3)=(g,v); H col = (n0>>1)+wn*32+(pair?16:0)+(lane&15)
#pragma unroll
    for (int m = 0; m < 4; ++m) {
#pragma unroll
        for (int j = 0; j < 4; ++j) {
            int rl = wm * 64 + m * 16 + (lane >> 4) * 4 + j;
            bf16* hb = H + (size_t)(rowBase + rl) * D_FF + (n0 >> 1) + wn * 32 + (lane & 15);
            {
                float g = acc[m][0][j], v = acc[m][1][j];
                hb[0] = (bf16)((g / (1.f + __expf(-g))) * v);
            }
            {
                float g = acc[m][2][j], v = acc[m][3][j];
                hb[16] = (bf16)((g / (1.f + __expf(-g))) * v);
            }
        }
    }
}

// ---------------- GEMM stage 2: O2[row] = w[row] * (H[row] @ W3) ----------------
// Grid: 1D 1088 blocks. XCD swizzle, n-minor within chunk.
__global__ __launch_bounds__(256, 3)
void gemm2_kernel(const bf16* __restrict__ H, const bf16* __restrict__ w3t,
                  bf16* __restrict__ O2, const int* __restrict__ ctrl,
                  const float* __restrict__ rowW) {
    const int L = blockIdx.x;
    const int xcd = L & 7;
    const int w = L >> 3;                 // 0..135
    const int n0 = (w & 7) * 128;
    const int mt = xcd * 17 + (w >> 3);   // 0..135
    if (mt >= ctrl[16]) return;
    const int e = ctrl[64 + mt];
    const int rowBase = ctrl[256 + mt];

    __shared__ char lds[32768];

    const int tid = threadIdx.x, lane = tid & 63;
    const int wm = (tid >> 7) & 1, wn = (tid >> 6) & 1;

    const bf16* w3b = w3t + (size_t)e * D_MODEL * D_FF;
    const bf16* aSrc[4]; const bf16* bSrc[4]; int dstOff[4];
#pragma unroll
    for (int rd = 0; rd < 4; ++rd) {
        int o = rd * 4096 + tid * 16;
        int r = o >> 7;
        int c2 = ((o >> 4) & 7) ^ (r & 7);
        dstOff[rd] = o;
        aSrc[rd] = H   + (size_t)(rowBase + r) * D_FF + c2 * 8;
        bSrc[rd] = w3b + (size_t)(n0 + r) * D_FF + c2 * 8;
    }

    f32x4 acc[4][4];
#pragma unroll
    for (int m = 0; m < 4; ++m)
#pragma unroll
        for (int n = 0; n < 4; ++n) acc[m][n] = (f32x4){0.f, 0.f, 0.f, 0.f};

    for (int kt = 0; kt < D_FF / 64; ++kt) {
#pragma unroll
        for (int rd = 0; rd < 4; ++rd) {
            gload16(aSrc[rd] + kt * 64, lds + dstOff[rd]);
            gload16(bSrc[rd] + kt * 64, lds + 16384 + dstOff[rd]);
        }
        __syncthreads();
#pragma unroll
        for (int ks = 0; ks < 2; ++ks) {
            bf16x8 af[4], bfr[4];
            int c2 = ks * 4 + (lane >> 4);
#pragma unroll
            for (int m = 0; m < 4; ++m) {
                int r = wm * 64 + m * 16 + (lane & 15);
                af[m] = *(const bf16x8*)(lds + r * 128 + ((c2 ^ (r & 7)) << 4));
            }
#pragma unroll
            for (int n = 0; n < 4; ++n) {
                int r = wn * 64 + n * 16 + (lane & 15);
                bfr[n] = *(const bf16x8*)(lds + 16384 + r * 128 + ((c2 ^ (r & 7)) << 4));
            }
#pragma unroll
            for (int m = 0; m < 4; ++m)
#pragma unroll
                for (int n = 0; n < 4; ++n)
                    acc[m][n] = __builtin_amdgcn_mfma_f32_16x16x32_bf16(af[m], bfr[n], acc[m][n], 0, 0, 0);
        }
        __syncthreads();
    }

#pragma unroll
    for (int m = 0; m < 4; ++m) {
#pragma unroll
        for (int j = 0; j < 4; ++j) {
            int rl = wm * 64 + m * 16 + (lane >> 4) * 4 + j;
            int row = rowBase + rl;
            float wgt = rowW[row];
            bf16* obase = O2 + (size_t)row * D_MODEL + n0 + wn * 64 + (lane & 15);
#pragma unroll
            for (int n = 0; n < 4; ++n)
                obase[n * 16] = (bf16)(wgt * acc[m][n][j]);
        }
    }
}

// ---------------- combine: out[t] = O2[rowOf[t,0]] + O2[rowOf[t,1]] ----------------
__global__ void combine_kernel(const bf16* __restrict__ O2, const int* __restrict__ rowOf,
                               float* __restrict__ out) {
    int t = blockIdx.x;
    int r0 = rowOf[t * 2 + 0], r1 = rowOf[t * 2 + 1];
    int c = threadIdx.x * 4;
    bf16x4 a = *(const bf16x4*)(O2 + (size_t)r0 * D_MODEL + c);
    bf16x4 b = *(const bf16x4*)(O2 + (size_t)r1 * D_MODEL + c);
    float4 o;
    o.x = (float)a[0] + (float)b[0];
    o.y = (float)a[1] + (float)b[1];
    o.z = (float)a[2] + (float)b[2];
    o.w = (float)a[3] + (float)b[3];
    *(float4*)(out + (size_t)t * D_MODEL + c) = o;
}

// ---------------- launch ----------------
extern "C" void kernel_launch(void* const* d_in, const int* in_sizes, int n_in,
                              void* d_out, int out_size, void* d_ws, size_t ws_size,
                              hipStream_t stream) {
    const float* x  = (const float*)d_in[0];
    const int*   ei = (const int*)d_in[1];
    const float* ew = (const float*)d_in[2];
    const float* w1 = (const float*)d_in[3];
    const float* w2 = (const float*)d_in[4];
    const float* w3 = (const float*)d_in[5];
    float* out = (float*)d_out;

    char* w = (char*)d_ws;
    constexpr size_t CTRL_OFF  = 0;
    constexpr size_t TOK_OFF   = 4096;
    constexpr size_t ROWW_OFF  = TOK_OFF + (size_t)MAX_ROWS * 4;       // 73728
    constexpr size_t ROWOF_OFF = ROWW_OFF + (size_t)MAX_ROWS * 4;      // 143360
    constexpr size_t XB_OFF    = ROWOF_OFF + (size_t)T_TOKENS * 2 * 4; // 274432
    constexpr size_t WC_OFF    = XB_OFF + (size_t)T_TOKENS * D_MODEL * 2;       // 16 MB later
    constexpr size_t W3T_OFF   = WC_OFF + (size_t)N_EXP * 4096 * 1024 * 2;      // +64 MB
    constexpr size_t H_OFF     = W3T_OFF + (size_t)N_EXP * D_MODEL * D_FF * 2;  // +32 MB
    // O2 (bf16, MAX_ROWS x D_MODEL = 35.7 MB) aliases wc (64 MB), dead after gemm1.
    constexpr size_t O2_OFF    = WC_OFF;

    int*   ctrl    = (int*)(w + CTRL_OFF);
    int*   tokenId = (int*)(w + TOK_OFF);
    float* rowW    = (float*)(w + ROWW_OFF);
    int*   rowOf   = (int*)(w + ROWOF_OFF);
    bf16*  xb      = (bf16*)(w + XB_OFF);
    bf16*  wc      = (bf16*)(w + WC_OFF);
    bf16*  w3t     = (bf16*)(w + W3T_OFF);
    bf16*  H       = (bf16*)(w + H_OFF);
    bf16*  O2      = (bf16*)(w + O2_OFF);

    hipMemsetAsync(ctrl, 0, 64, stream);  // counts + cursors

    count_kernel<<<T_TOKENS / 256, 256, 0, stream>>>(ei, ctrl);
    scan_kernel<<<1, 256, 0, stream>>>(ctrl, tokenId, rowW);
    scatter_kernel<<<T_TOKENS / 256, 256, 0, stream>>>(ei, ew, ctrl, tokenId, rowW, rowOf);

    cvtx_kernel<<<(T_TOKENS * D_MODEL) / (256 * 8), 256, 0, stream>>>(x, xb);
    // W1 -> even 16-col blocks of wc, W2 -> odd; W3 -> plain transposed.
    // outMatStride: wc is [E][4096][1024]; w3t is [E][1024][2048].
    tconv_kernel<<<dim3(D_FF / 32, D_MODEL / 32, N_EXP), 256, 0, stream>>>(w1, wc, D_MODEL, D_FF, (size_t)4096 * 1024, 1);
    tconv_kernel<<<dim3(D_FF / 32, D_MODEL / 32, N_EXP), 256, 0, stream>>>(w2, wc, D_MODEL, D_FF, (size_t)4096 * 1024, 2);
    tconv_kernel<<<dim3(D_MODEL / 32, D_FF / 32, N_EXP), 256, 0, stream>>>(w3, w3t, D_FF, D_MODEL, (size_t)D_FF * D_MODEL, 0);

    gemm1_kernel<<<MAX_MT * (4096 / 128), 256, 0, stream>>>(xb, wc, H, ctrl, tokenId);
    gemm2_kernel<<<MAX_MT * (D_MODEL / 128), 256, 0, stream>>>(H, w3t, O2, ctrl, rowW);
    combine_kernel<<<T_TOKENS, 256, 0, stream>>>(O2, rowOf, out);
}

// Round 8
// 381.358 us; speedup vs baseline: 1.3125x; 1.0224x over previous
//
#include <hip/hip_runtime.h>
#include <hip/hip_bf16.h>
#include <cstdint>
#include <cstddef>

typedef __bf16 bf16;
typedef __attribute__((ext_vector_type(4))) float f32x4;
typedef __attribute__((ext_vector_type(8))) __bf16 bf16x8;
typedef __attribute__((ext_vector_type(4))) __bf16 bf16x4;

// ---------------- constants ----------------
#define T_TOKENS 8192
#define D_MODEL  1024
#define D_FF     2048
#define N_EXP    8
#define MAX_ROWS 17408   // 16384 + 8*128 padding
#define MAX_MT   136     // max m-tiles of 128 (8 XCD chunks of 17)

// ctrl layout (int indices): counts[0..7], cursors[8..15], numTiles[16],
// pstart[32..40], tileExpert[64..199], tileRow[256..391]

__device__ __forceinline__ void gload16(const void* g, void* l) {
    __builtin_amdgcn_global_load_lds((const __attribute__((address_space(1))) void*)g,
                                     (__attribute__((address_space(3))) void*)l, 16, 0, 0);
}

// ---------------- dispatch building ----------------
__global__ void count_kernel(const int* __restrict__ ei, int* __restrict__ ctrl,
                             int* __restrict__ tokenId, float* __restrict__ rowW) {
    // zero-init padded row list (32 blocks; replaces serial pass in scan)
    int gid = blockIdx.x * blockDim.x + threadIdx.x;
    for (int r = gid; r < MAX_ROWS; r += T_TOKENS) { tokenId[r] = 0; rowW[r] = 0.f; }

    __shared__ int lc[N_EXP];
    if (threadIdx.x < N_EXP) lc[threadIdx.x] = 0;
    __syncthreads();
    int t = gid;
    if (t < T_TOKENS) {
        atomicAdd(&lc[ei[t * 2 + 0]], 1);
        atomicAdd(&lc[ei[t * 2 + 1]], 1);
    }
    __syncthreads();
    if (threadIdx.x < N_EXP) atomicAdd(&ctrl[threadIdx.x], lc[threadIdx.x]);
}

__global__ void scan_kernel(int* __restrict__ ctrl) {
    if (threadIdx.x == 0) {
        int s = 0, nt = 0;
        for (int e = 0; e < N_EXP; ++e) {
            ctrl[32 + e] = s;
            int cnt = ctrl[e];
            int tiles = (cnt + 127) >> 7;
            for (int i = 0; i < tiles; ++i) { ctrl[64 + nt] = e; ctrl[256 + nt] = s + (i << 7); ++nt; }
            s += tiles << 7;
        }
        ctrl[32 + 8] = s;
        ctrl[16] = nt;
    }
}

__global__ void scatter_kernel(const int* __restrict__ ei, const float* __restrict__ ew,
                               int* __restrict__ ctrl, int* __restrict__ tokenId,
                               float* __restrict__ rowW, int* __restrict__ rowOf) {
    int t = blockIdx.x * blockDim.x + threadIdx.x;
    if (t >= T_TOKENS) return;
    for (int k = 0; k < 2; ++k) {
        int e = ei[t * 2 + k];
        int pos = atomicAdd(&ctrl[8 + e], 1);
        int r = ctrl[32 + e] + pos;
        tokenId[r] = t;
        rowW[r] = ew[t * 2 + k];
        rowOf[t * 2 + k] = r;
    }
}

// ---------------- conversions ----------------
__global__ void cvtx_kernel(const float* __restrict__ x, bf16* __restrict__ xb) {
    int i = (blockIdx.x * 256 + threadIdx.x) * 8;
    float4 v0 = *(const float4*)(x + i);
    float4 v1 = *(const float4*)(x + i + 4);
    bf16x8 o;
    o[0] = (bf16)v0.x; o[1] = (bf16)v0.y; o[2] = (bf16)v0.z; o[3] = (bf16)v0.w;
    o[4] = (bf16)v1.x; o[5] = (bf16)v1.y; o[6] = (bf16)v1.z; o[7] = (bf16)v1.w;
    *(bf16x8*)(xb + i) = o;
}

// transpose-convert: in fp32 [E][R][C] -> out bf16 [E][f(C)][R]
// mode 0: f(c)=c (plain). mode 1: f(c)=(c>>4)*32+(c&15)      (W1 -> even 16-col blocks)
//                          mode 2: f(c)=(c>>4)*32+16+(c&15)   (W2 -> odd 16-col blocks)
// 64x64 tile, float4 reads, uint2 (4x bf16) writes. 2-way LDS bank alias only (free).
__global__ __launch_bounds__(256)
void tconv_kernel(const float* __restrict__ in, bf16* __restrict__ out,
                  int R, int C, size_t outMatStride, int mode) {
    __shared__ float tile[64][65];
    const float* src = in + (size_t)R * C * blockIdx.z;
    bf16* dst = out + outMatStride * blockIdx.z;
    const int c0 = blockIdx.x * 64, r0 = blockIdx.y * 64;
    const int t = threadIdx.x;
    const int cg = (t & 15) * 4;     // load: col group
    const int rq = t >> 4;           // load: row within 16-row stripe
#pragma unroll
    for (int p = 0; p < 4; ++p) {
        int rl = p * 16 + rq;
        float4 v = *(const float4*)(src + (size_t)(r0 + rl) * C + c0 + cg);
        tile[rl][cg + 0] = v.x; tile[rl][cg + 1] = v.y;
        tile[rl][cg + 2] = v.z; tile[rl][cg + 3] = v.w;
    }
    __syncthreads();
    const int q = t & 15;            // store: row-quad index (rows 4q..4q+3)
    const int cs = t >> 4;           // store: col within 16-col stripe
#pragma unroll
    for (int p = 0; p < 4; ++p) {
        int cl = p * 16 + cs;
        int c = c0 + cl;
        int dcol = (mode == 0) ? c : (((c >> 4) << 5) + ((mode == 2) ? 16 : 0) + (c & 15));
        bf16 b0 = (bf16)tile[4 * q + 0][cl];
        bf16 b1 = (bf16)tile[4 * q + 1][cl];
        bf16 b2 = (bf16)tile[4 * q + 2][cl];
        bf16 b3 = (bf16)tile[4 * q + 3][cl];
        uint2 pk;
        pk.x = ((uint32_t)*(uint16_t*)&b1 << 16) | *(uint16_t*)&b0;
        pk.y = ((uint32_t)*(uint16_t*)&b3 << 16) | *(uint16_t*)&b2;
        *(uint2*)(dst + (size_t)dcol * R + r0 + 4 * q) = pk;
    }
}

// ---------------- GEMM stage 1: H = silu(X Wc_even) * (X Wc_odd), gathered rows ----
// Combined B: wc [E][4096][1024] bf16 (row = combined col, K contiguous).
// m97-style 2-barrier single-buffer loop; 3 blocks/CU.
// Grid: 1D 4352 blocks, XCD-locality swizzle (xcd = L&7 owns m-tiles chunk).
__global__ __launch_bounds__(256, 3)
void gemm1_kernel(const bf16* __restrict__ xb, const bf16* __restrict__ wc,
                  bf16* __restrict__ H, const int* __restrict__ ctrl,
                  const int* __restrict__ tokenId) {
    const int L = blockIdx.x;
    const int xcd = L & 7;
    const int w = L >> 3;                 // 0..543
    const int mt = xcd * 17 + (w % 17);   // 0..135
    const int n0 = (w / 17) * 128;        // combined-col tile base (0..4095)
    if (mt >= ctrl[16]) return;
    const int e = ctrl[64 + mt];
    const int rowBase = ctrl[256 + mt];

    __shared__ char lds[32768];        // A: [0,16384)  B: [16384,32768)

    const int tid = threadIdx.x, lane = tid & 63;
    const int wm = (tid >> 7) & 1, wn = (tid >> 6) & 1;

    const bf16* wb = wc + (size_t)e * 4096 * 1024;

    const bf16* aSrc[4]; const bf16* bSrc[4]; int dstOff[4];
#pragma unroll
    for (int rd = 0; rd < 4; ++rd) {
        int o = rd * 4096 + tid * 16;
        int r = o >> 7;                    // row 0..127
        int c2 = ((o >> 4) & 7) ^ (r & 7); // pre-swizzled source slot
        dstOff[rd] = o;
        int tok = tokenId[rowBase + r];
        aSrc[rd] = xb + (size_t)tok * D_MODEL + c2 * 8;
        bSrc[rd] = wb + (size_t)(n0 + r) * D_MODEL + c2 * 8;
    }

    f32x4 acc[4][4];
#pragma unroll
    for (int m = 0; m < 4; ++m)
#pragma unroll
        for (int n = 0; n < 4; ++n) acc[m][n] = (f32x4){0.f, 0.f, 0.f, 0.f};

    for (int kt = 0; kt < D_MODEL / 64; ++kt) {
#pragma unroll
        for (int rd = 0; rd < 4; ++rd) {
            gload16(aSrc[rd] + kt * 64, lds + dstOff[rd]);
            gload16(bSrc[rd] + kt * 64, lds + 16384 + dstOff[rd]);
        }
        __syncthreads();   // drains vmcnt before any wave reads
#pragma unroll
        for (int ks = 0; ks < 2; ++ks) {
            bf16x8 af[4], bfr[4];
            int c2 = ks * 4 + (lane >> 4);
#pragma unroll
            for (int m = 0; m < 4; ++m) {
                int r = wm * 64 + m * 16 + (lane & 15);
                af[m] = *(const bf16x8*)(lds + r * 128 + ((c2 ^ (r & 7)) << 4));
            }
#pragma unroll
            for (int n = 0; n < 4; ++n) {
                int r = wn * 64 + n * 16 + (lane & 15);
                bfr[n] = *(const bf16x8*)(lds + 16384 + r * 128 + ((c2 ^ (r & 7)) << 4));
            }
#pragma unroll
            for (int m = 0; m < 4; ++m)
#pragma unroll
                for (int n = 0; n < 4; ++n)
                    acc[m][n] = __builtin_amdgcn_mfma_f32_16x16x32_bf16(af[m], bfr[n], acc[m][n], 0, 0, 0);
        }
        __syncthreads();   // all waves done reading before next stage overwrites
    }

    // epilogue: n-frag pairs (0,1)=(g,v) and (2,3)=(g,v); H col = (n0>>1)+wn*32+(pair?16:0)+(lane&15)
#pragma unroll
    for (int m = 0; m < 4; ++m) {
#pragma unroll
        for (int j = 0; j < 4; ++j) {
            int rl = wm * 64 + m * 16 + (lane >> 4) * 4 + j;
            bf16* hb = H + (size_t)(rowBase + rl) * D_FF + (n0 >> 1) + wn * 32 + (lane & 15);
            {
                float g = acc[m][0][j], v = acc[m][1][j];
                hb[0] = (bf16)((g / (1.f + __expf(-g))) * v);
            }
            {
                float g = acc[m][2][j], v = acc[m][3][j];
                hb[16] = (bf16)((g / (1.f + __expf(-g))) * v);
            }
        }
    }
}

// ---------------- GEMM stage 2: O2[row] = w[row] * (H[row] @ W3) ----------------
// Grid: 1D 1088 blocks. XCD swizzle, n-minor within chunk.
__global__ __launch_bounds__(256, 3)
void gemm2_kernel(const bf16* __restrict__ H, const bf16* __restrict__ w3t,
                  bf16* __restrict__ O2, const int* __restrict__ ctrl,
                  const float* __restrict__ rowW) {
    const int L = blockIdx.x;
    const int xcd = L & 7;
    const int w = L >> 3;                 // 0..135
    const int n0 = (w & 7) * 128;
    const int mt = xcd * 17 + (w >> 3);   // 0..135
    if (mt >= ctrl[16]) return;
    const int e = ctrl[64 + mt];
    const int rowBase = ctrl[256 + mt];

    __shared__ char lds[32768];

    const int tid = threadIdx.x, lane = tid & 63;
    const int wm = (tid >> 7) & 1, wn = (tid >> 6) & 1;

    const bf16* w3b = w3t + (size_t)e * D_MODEL * D_FF;
    const bf16* aSrc[4]; const bf16* bSrc[4]; int dstOff[4];
#pragma unroll
    for (int rd = 0; rd < 4; ++rd) {
        int o = rd * 4096 + tid * 16;
        int r = o >> 7;
        int c2 = ((o >> 4) & 7) ^ (r & 7);
        dstOff[rd] = o;
        aSrc[rd] = H   + (size_t)(rowBase + r) * D_FF + c2 * 8;
        bSrc[rd] = w3b + (size_t)(n0 + r) * D_FF + c2 * 8;
    }

    f32x4 acc[4][4];
#pragma unroll
    for (int m = 0; m < 4; ++m)
#pragma unroll
        for (int n = 0; n < 4; ++n) acc[m][n] = (f32x4){0.f, 0.f, 0.f, 0.f};

    for (int kt = 0; kt < D_FF / 64; ++kt) {
#pragma unroll
        for (int rd = 0; rd < 4; ++rd) {
            gload16(aSrc[rd] + kt * 64, lds + dstOff[rd]);
            gload16(bSrc[rd] + kt * 64, lds + 16384 + dstOff[rd]);
        }
        __syncthreads();
#pragma unroll
        for (int ks = 0; ks < 2; ++ks) {
            bf16x8 af[4], bfr[4];
            int c2 = ks * 4 + (lane >> 4);
#pragma unroll
            for (int m = 0; m < 4; ++m) {
                int r = wm * 64 + m * 16 + (lane & 15);
                af[m] = *(const bf16x8*)(lds + r * 128 + ((c2 ^ (r & 7)) << 4));
            }
#pragma unroll
            for (int n = 0; n < 4; ++n) {
                int r = wn * 64 + n * 16 + (lane & 15);
                bfr[n] = *(const bf16x8*)(lds + 16384 + r * 128 + ((c2 ^ (r & 7)) << 4));
            }
#pragma unroll
            for (int m = 0; m < 4; ++m)
#pragma unroll
                for (int n = 0; n < 4; ++n)
                    acc[m][n] = __builtin_amdgcn_mfma_f32_16x16x32_bf16(af[m], bfr[n], acc[m][n], 0, 0, 0);
        }
        __syncthreads();
    }

#pragma unroll
    for (int m = 0; m < 4; ++m) {
#pragma unroll
        for (int j = 0; j < 4; ++j) {
            int rl = wm * 64 + m * 16 + (lane >> 4) * 4 + j;
            int row = rowBase + rl;
            float wgt = rowW[row];
            bf16* obase = O2 + (size_t)row * D_MODEL + n0 + wn * 64 + (lane & 15);
#pragma unroll
            for (int n = 0; n < 4; ++n)
                obase[n * 16] = (bf16)(wgt * acc[m][n][j]);
        }
    }
}

// ---------------- combine: out[t] = O2[rowOf[t,0]] + O2[rowOf[t,1]] ----------------
__global__ void combine_kernel(const bf16* __restrict__ O2, const int* __restrict__ rowOf,
                               float* __restrict__ out) {
    int t = blockIdx.x;
    int r0 = rowOf[t * 2 + 0], r1 = rowOf[t * 2 + 1];
    int c = threadIdx.x * 4;
    bf16x4 a = *(const bf16x4*)(O2 + (size_t)r0 * D_MODEL + c);
    bf16x4 b = *(const bf16x4*)(O2 + (size_t)r1 * D_MODEL + c);
    float4 o;
    o.x = (float)a[0] + (float)b[0];
    o.y = (float)a[1] + (float)b[1];
    o.z = (float)a[2] + (float)b[2];
    o.w = (float)a[3] + (float)b[3];
    *(float4*)(out + (size_t)t * D_MODEL + c) = o;
}

// ---------------- launch ----------------
extern "C" void kernel_launch(void* const* d_in, const int* in_sizes, int n_in,
                              void* d_out, int out_size, void* d_ws, size_t ws_size,
                              hipStream_t stream) {
    const float* x  = (const float*)d_in[0];
    const int*   ei = (const int*)d_in[1];
    const float* ew = (const float*)d_in[2];
    const float* w1 = (const float*)d_in[3];
    const float* w2 = (const float*)d_in[4];
    const float* w3 = (const float*)d_in[5];
    float* out = (float*)d_out;

    char* w = (char*)d_ws;
    constexpr size_t CTRL_OFF  = 0;
    constexpr size_t TOK_OFF   = 4096;
    constexpr size_t ROWW_OFF  = TOK_OFF + (size_t)MAX_ROWS * 4;       // 73728
    constexpr size_t ROWOF_OFF = ROWW_OFF + (size_t)MAX_ROWS * 4;      // 143360
    constexpr size_t XB_OFF    = ROWOF_OFF + (size_t)T_TOKENS * 2 * 4; // 274432
    constexpr size_t WC_OFF    = XB_OFF + (size_t)T_TOKENS * D_MODEL * 2;       // 16 MB later
    constexpr size_t W3T_OFF   = WC_OFF + (size_t)N_EXP * 4096 * 1024 * 2;      // +64 MB
    constexpr size_t H_OFF     = W3T_OFF + (size_t)N_EXP * D_MODEL * D_FF * 2;  // +32 MB
    // O2 (bf16, MAX_ROWS x D_MODEL = 35.7 MB) aliases wc (64 MB), dead after gemm1.
    constexpr size_t O2_OFF    = WC_OFF;

    int*   ctrl    = (int*)(w + CTRL_OFF);
    int*   tokenId = (int*)(w + TOK_OFF);
    float* rowW    = (float*)(w + ROWW_OFF);
    int*   rowOf   = (int*)(w + ROWOF_OFF);
    bf16*  xb      = (bf16*)(w + XB_OFF);
    bf16*  wc      = (bf16*)(w + WC_OFF);
    bf16*  w3t     = (bf16*)(w + W3T_OFF);
    bf16*  H       = (bf16*)(w + H_OFF);
    bf16*  O2      = (bf16*)(w + O2_OFF);

    hipMemsetAsync(ctrl, 0, 64, stream);  // counts + cursors

    count_kernel<<<T_TOKENS / 256, 256, 0, stream>>>(ei, ctrl, tokenId, rowW);
    scan_kernel<<<1, 64, 0, stream>>>(ctrl);
    scatter_kernel<<<T_TOKENS / 256, 256, 0, stream>>>(ei, ew, ctrl, tokenId, rowW, rowOf);

    cvtx_kernel<<<(T_TOKENS * D_MODEL) / (256 * 8), 256, 0, stream>>>(x, xb);
    // W1 -> even 16-col blocks of wc, W2 -> odd; W3 -> plain transposed.
    // outMatStride: wc is [E][4096][1024]; w3t is [E][1024][2048].
    tconv_kernel<<<dim3(D_FF / 64, D_MODEL / 64, N_EXP), 256, 0, stream>>>(w1, wc, D_MODEL, D_FF, (size_t)4096 * 1024, 1);
    tconv_kernel<<<dim3(D_FF / 64, D_MODEL / 64, N_EXP), 256, 0, stream>>>(w2, wc, D_MODEL, D_FF, (size_t)4096 * 1024, 2);
    tconv_kernel<<<dim3(D_MODEL / 64, D_FF / 64, N_EXP), 256, 0, stream>>>(w3, w3t, D_FF, D_MODEL, (size_t)D_FF * D_MODEL, 0);

    gemm1_kernel<<<MAX_MT * (4096 / 128), 256, 0, stream>>>(xb, wc, H, ctrl, tokenId);
    gemm2_kernel<<<MAX_MT * (D_MODEL / 128), 256, 0, stream>>>(H, w3t, O2, ctrl, rowW);
    combine_kernel<<<T_TOKENS, 256, 0, stream>>>(O2, rowOf, out);
}

// Round 9
// 370.814 us; speedup vs baseline: 1.3498x; 1.0284x over previous
//
#include <hip/hip_runtime.h>
#include <hip/hip_bf16.h>
#include <cstdint>
#include <cstddef>

typedef __bf16 bf16;
typedef __attribute__((ext_vector_type(4))) float f32x4;
typedef __attribute__((ext_vector_type(8))) __bf16 bf16x8;
typedef __attribute__((ext_vector_type(4))) __bf16 bf16x4;

// ---------------- constants ----------------
#define T_TOKENS 8192
#define D_MODEL  1024
#define D_FF     2048
#define N_EXP    8
#define MAX_ROWS 17408   // 16384 + 8*128 padding
#define MAX_MT   136     // max m-tiles of 128 (8 XCD chunks of 17)

// ctrl layout (int indices): numTiles[16], pstart[32..40],
// tileExpert[64..199], tileRow[256..391]

__device__ __forceinline__ void gload16(const void* g, void* l) {
    __builtin_amdgcn_global_load_lds((const __attribute__((address_space(1))) void*)g,
                                     (__attribute__((address_space(3))) void*)l, 16, 0, 0);
}

// ---------------- fused prep: weight transposes + x convert + dispatch build ----
// grid (32,32,29), 256 threads.
//   z in [0,8):  W1 expert z  -> wc even 16-col blocks (mode 1)
//   z in [8,16): W2 expert z-8 -> wc odd 16-col blocks (mode 2)
//   z in [16,24): W3 expert z-16 -> w3t plain (mode 0)
//   z in [24,28): cvtx, virtual block (z-24)*1024 + y*32 + x
//   z == 28, block (0,0): dispatch build (count/scan/scatter/pad) in one block,
//   overlapped with the conversion blocks (no serial tiny-launch chain).
__global__ __launch_bounds__(256)
void prep_kernel(const float* __restrict__ x, bf16* __restrict__ xb,
                 const float* __restrict__ w1, const float* __restrict__ w2,
                 const float* __restrict__ w3, bf16* __restrict__ wc,
                 bf16* __restrict__ w3t,
                 const int* __restrict__ ei, const float* __restrict__ ew,
                 int* __restrict__ ctrl, int* __restrict__ tokenId,
                 float* __restrict__ rowW, int* __restrict__ rowOf) {
    const int z = blockIdx.z;
    const int t = threadIdx.x;

    if (z >= 24) {
        if (z == 28) {
            // ---- dispatch build: single block ----
            if (blockIdx.x != 0 || blockIdx.y != 0) return;
            __shared__ int lc[N_EXP], cur[N_EXP], ps[N_EXP], padS[N_EXP], padE[N_EXP];
            if (t < N_EXP) { lc[t] = 0; cur[t] = 0; }
            __syncthreads();
            for (int i = t; i < T_TOKENS * 2; i += 256)
                atomicAdd(&lc[ei[i]], 1);
            __syncthreads();
            if (t == 0) {
                int s = 0, nt = 0;
                for (int e = 0; e < N_EXP; ++e) {
                    ps[e] = s;
                    ctrl[32 + e] = s;
                    int cnt = lc[e];
                    int tiles = (cnt + 127) >> 7;
                    for (int i = 0; i < tiles; ++i) {
                        ctrl[64 + nt] = e; ctrl[256 + nt] = s + (i << 7); ++nt;
                    }
                    padS[e] = s + cnt; padE[e] = s + (tiles << 7);
                    s += tiles << 7;
                }
                ctrl[16] = nt;
            }
            __syncthreads();
            // scatter (LDS cursors; row-slot order is run-varying but the final
            // output is identical regardless of within-expert row permutation)
            for (int i = t; i < T_TOKENS * 2; i += 256) {
                int e = ei[i];
                int pos = atomicAdd(&cur[e], 1);
                int r = ps[e] + pos;
                tokenId[r] = i >> 1;
                rowW[r] = ew[i];
                rowOf[i] = r;
            }
            // zero only the padding rows (scatter covers all non-pad rows)
            for (int e = 0; e < N_EXP; ++e)
                for (int r = padS[e] + t; r < padE[e]; r += 256) {
                    tokenId[r] = 0; rowW[r] = 0.f;
                }
            return;
        }
        // ---- cvtx: x fp32 -> xb bf16, 8 elems/thread ----
        int bid = (z - 24) * 1024 + blockIdx.y * 32 + blockIdx.x;
        int i = (bid * 256 + t) * 8;
        float4 v0 = *(const float4*)(x + i);
        float4 v1 = *(const float4*)(x + i + 4);
        bf16x8 o;
        o[0] = (bf16)v0.x; o[1] = (bf16)v0.y; o[2] = (bf16)v0.z; o[3] = (bf16)v0.w;
        o[4] = (bf16)v1.x; o[5] = (bf16)v1.y; o[6] = (bf16)v1.z; o[7] = (bf16)v1.w;
        *(bf16x8*)(xb + i) = o;
        return;
    }

    // ---- tconv: fp32 [R][C] -> bf16 [f(C)][R] for one expert ----
    int R, C, mode;
    const float* src;
    bf16* dst;
    if (z < 8)       { R = D_MODEL; C = D_FF;    mode = 1; src = w1 + (size_t)z * R * C;        dst = wc  + (size_t)z * 4096 * 1024; }
    else if (z < 16) { R = D_MODEL; C = D_FF;    mode = 2; src = w2 + (size_t)(z - 8) * R * C;  dst = wc  + (size_t)(z - 8) * 4096 * 1024; }
    else             { R = D_FF;    C = D_MODEL; mode = 0; src = w3 + (size_t)(z - 16) * R * C; dst = w3t + (size_t)(z - 16) * D_FF * D_MODEL; }
    const int c0 = blockIdx.x * 64, r0 = blockIdx.y * 64;
    if (c0 >= C || r0 >= R) return;

    __shared__ float tile[64][65];
    const int cg = (t & 15) * 4;     // load: col group
    const int rq = t >> 4;           // load: row within 16-row stripe
#pragma unroll
    for (int p = 0; p < 4; ++p) {
        int rl = p * 16 + rq;
        float4 v = *(const float4*)(src + (size_t)(r0 + rl) * C + c0 + cg);
        tile[rl][cg + 0] = v.x; tile[rl][cg + 1] = v.y;
        tile[rl][cg + 2] = v.z; tile[rl][cg + 3] = v.w;
    }
    __syncthreads();
    const int q = t & 15;            // store: row-quad index (rows 4q..4q+3)
    const int cs = t >> 4;           // store: col within 16-col stripe
#pragma unroll
    for (int p = 0; p < 4; ++p) {
        int cl = p * 16 + cs;
        int c = c0 + cl;
        int dcol = (mode == 0) ? c : (((c >> 4) << 5) + ((mode == 2) ? 16 : 0) + (c & 15));
        bf16 b0 = (bf16)tile[4 * q + 0][cl];
        bf16 b1 = (bf16)tile[4 * q + 1][cl];
        bf16 b2 = (bf16)tile[4 * q + 2][cl];
        bf16 b3 = (bf16)tile[4 * q + 3][cl];
        uint2 pk;
        pk.x = ((uint32_t)*(uint16_t*)&b1 << 16) | *(uint16_t*)&b0;
        pk.y = ((uint32_t)*(uint16_t*)&b3 << 16) | *(uint16_t*)&b2;
        *(uint2*)(dst + (size_t)dcol * R + r0 + 4 * q) = pk;
    }
}

// ---------------- GEMM stage 1: H = silu(X Wc_even) * (X Wc_odd), gathered rows ----
// Combined B: wc [E][4096][1024] bf16 (row = combined col, K contiguous).
// m97-style 2-barrier single-buffer loop; 3 blocks/CU.
// Grid: 1D 4352 blocks, XCD-locality swizzle (xcd = L&7 owns m-tiles chunk).
__global__ __launch_bounds__(256, 3)
void gemm1_kernel(const bf16* __restrict__ xb, const bf16* __restrict__ wc,
                  bf16* __restrict__ H, const int* __restrict__ ctrl,
                  const int* __restrict__ tokenId) {
    const int L = blockIdx.x;
    const int xcd = L & 7;
    const int w = L >> 3;                 // 0..543
    const int mt = xcd * 17 + (w % 17);   // 0..135
    const int n0 = (w / 17) * 128;        // combined-col tile base (0..4095)
    if (mt >= ctrl[16]) return;
    const int e = ctrl[64 + mt];
    const int rowBase = ctrl[256 + mt];

    __shared__ char lds[32768];        // A: [0,16384)  B: [16384,32768)

    const int tid = threadIdx.x, lane = tid & 63;
    const int wm = (tid >> 7) & 1, wn = (tid >> 6) & 1;

    const bf16* wb = wc + (size_t)e * 4096 * 1024;

    const bf16* aSrc[4]; const bf16* bSrc[4]; int dstOff[4];
#pragma unroll
    for (int rd = 0; rd < 4; ++rd) {
        int o = rd * 4096 + tid * 16;
        int r = o >> 7;                    // row 0..127
        int c2 = ((o >> 4) & 7) ^ (r & 7); // pre-swizzled source slot
        dstOff[rd] = o;
        int tok = tokenId[rowBase + r];
        aSrc[rd] = xb + (size_t)tok * D_MODEL + c2 * 8;
        bSrc[rd] = wb + (size_t)(n0 + r) * D_MODEL + c2 * 8;
    }

    f32x4 acc[4][4];
#pragma unroll
    for (int m = 0; m < 4; ++m)
#pragma unroll
        for (int n = 0; n < 4; ++n) acc[m][n] = (f32x4){0.f, 0.f, 0.f, 0.f};

    for (int kt = 0; kt < D_MODEL / 64; ++kt) {
#pragma unroll
        for (int rd = 0; rd < 4; ++rd) {
            gload16(aSrc[rd] + kt * 64, lds + dstOff[rd]);
            gload16(bSrc[rd] + kt * 64, lds + 16384 + dstOff[rd]);
        }
        __syncthreads();   // drains vmcnt before any wave reads
#pragma unroll
        for (int ks = 0; ks < 2; ++ks) {
            bf16x8 af[4], bfr[4];
            int c2 = ks * 4 + (lane >> 4);
#pragma unroll
            for (int m = 0; m < 4; ++m) {
                int r = wm * 64 + m * 16 + (lane & 15);
                af[m] = *(const bf16x8*)(lds + r * 128 + ((c2 ^ (r & 7)) << 4));
            }
#pragma unroll
            for (int n = 0; n < 4; ++n) {
                int r = wn * 64 + n * 16 + (lane & 15);
                bfr[n] = *(const bf16x8*)(lds + 16384 + r * 128 + ((c2 ^ (r & 7)) << 4));
            }
#pragma unroll
            for (int m = 0; m < 4; ++m)
#pragma unroll
                for (int n = 0; n < 4; ++n)
                    acc[m][n] = __builtin_amdgcn_mfma_f32_16x16x32_bf16(af[m], bfr[n], acc[m][n], 0, 0, 0);
        }
        __syncthreads();   // all waves done reading before next stage overwrites
    }

    // epilogue: n-frag pairs (0,1)=(g,v) and (2,3)=(g,v); H col = (n0>>1)+wn*32+(pair?16:0)+(lane&15)
#pragma unroll
    for (int m = 0; m < 4; ++m) {
#pragma unroll
        for (int j = 0; j < 4; ++j) {
            int rl = wm * 64 + m * 16 + (lane >> 4) * 4 + j;
            bf16* hb = H + (size_t)(rowBase + rl) * D_FF + (n0 >> 1) + wn * 32 + (lane & 15);
            {
                float g = acc[m][0][j], v = acc[m][1][j];
                hb[0] = (bf16)((g / (1.f + __expf(-g))) * v);
            }
            {
                float g = acc[m][2][j], v = acc[m][3][j];
                hb[16] = (bf16)((g / (1.f + __expf(-g))) * v);
            }
        }
    }
}

// ---------------- GEMM stage 2: O2[row] = w[row] * (H[row] @ W3) ----------------
// Grid: 1D 1088 blocks. XCD swizzle, n-minor within chunk.
__global__ __launch_bounds__(256, 3)
void gemm2_kernel(const bf16* __restrict__ H, const bf16* __restrict__ w3t,
                  bf16* __restrict__ O2, const int* __restrict__ ctrl,
                  const float* __restrict__ rowW) {
    const int L = blockIdx.x;
    const int xcd = L & 7;
    const int w = L >> 3;                 // 0..135
    const int n0 = (w & 7) * 128;
    const int mt = xcd * 17 + (w >> 3);   // 0..135
    if (mt >= ctrl[16]) return;
    const int e = ctrl[64 + mt];
    const int rowBase = ctrl[256 + mt];

    __shared__ char lds[32768];

    const int tid = threadIdx.x, lane = tid & 63;
    const int wm = (tid >> 7) & 1, wn = (tid >> 6) & 1;

    const bf16* w3b = w3t + (size_t)e * D_MODEL * D_FF;
    const bf16* aSrc[4]; const bf16* bSrc[4]; int dstOff[4];
#pragma unroll
    for (int rd = 0; rd < 4; ++rd) {
        int o = rd * 4096 + tid * 16;
        int r = o >> 7;
        int c2 = ((o >> 4) & 7) ^ (r & 7);
        dstOff[rd] = o;
        aSrc[rd] = H   + (size_t)(rowBase + r) * D_FF + c2 * 8;
        bSrc[rd] = w3b + (size_t)(n0 + r) * D_FF + c2 * 8;
    }

    f32x4 acc[4][4];
#pragma unroll
    for (int m = 0; m < 4; ++m)
#pragma unroll
        for (int n = 0; n < 4; ++n) acc[m][n] = (f32x4){0.f, 0.f, 0.f, 0.f};

    for (int kt = 0; kt < D_FF / 64; ++kt) {
#pragma unroll
        for (int rd = 0; rd < 4; ++rd) {
            gload16(aSrc[rd] + kt * 64, lds + dstOff[rd]);
            gload16(bSrc[rd] + kt * 64, lds + 16384 + dstOff[rd]);
        }
        __syncthreads();
#pragma unroll
        for (int ks = 0; ks < 2; ++ks) {
            bf16x8 af[4], bfr[4];
            int c2 = ks * 4 + (lane >> 4);
#pragma unroll
            for (int m = 0; m < 4; ++m) {
                int r = wm * 64 + m * 16 + (lane & 15);
                af[m] = *(const bf16x8*)(lds + r * 128 + ((c2 ^ (r & 7)) << 4));
            }
#pragma unroll
            for (int n = 0; n < 4; ++n) {
                int r = wn * 64 + n * 16 + (lane & 15);
                bfr[n] = *(const bf16x8*)(lds + 16384 + r * 128 + ((c2 ^ (r & 7)) << 4));
            }
#pragma unroll
            for (int m = 0; m < 4; ++m)
#pragma unroll
                for (int n = 0; n < 4; ++n)
                    acc[m][n] = __builtin_amdgcn_mfma_f32_16x16x32_bf16(af[m], bfr[n], acc[m][n], 0, 0, 0);
        }
        __syncthreads();
    }

#pragma unroll
    for (int m = 0; m < 4; ++m) {
#pragma unroll
        for (int j = 0; j < 4; ++j) {
            int rl = wm * 64 + m * 16 + (lane >> 4) * 4 + j;
            int row = rowBase + rl;
            float wgt = rowW[row];
            bf16* obase = O2 + (size_t)row * D_MODEL + n0 + wn * 64 + (lane & 15);
#pragma unroll
            for (int n = 0; n < 4; ++n)
                obase[n * 16] = (bf16)(wgt * acc[m][n][j]);
        }
    }
}

// ---------------- combine: out[t] = O2[rowOf[t,0]] + O2[rowOf[t,1]] ----------------
__global__ void combine_kernel(const bf16* __restrict__ O2, const int* __restrict__ rowOf,
                               float* __restrict__ out) {
    int t = blockIdx.x;
    int r0 = rowOf[t * 2 + 0], r1 = rowOf[t * 2 + 1];
    int c = threadIdx.x * 4;
    bf16x4 a = *(const bf16x4*)(O2 + (size_t)r0 * D_MODEL + c);
    bf16x4 b = *(const bf16x4*)(O2 + (size_t)r1 * D_MODEL + c);
    float4 o;
    o.x = (float)a[0] + (float)b[0];
    o.y = (float)a[1] + (float)b[1];
    o.z = (float)a[2] + (float)b[2];
    o.w = (float)a[3] + (float)b[3];
    *(float4*)(out + (size_t)t * D_MODEL + c) = o;
}

// ---------------- launch ----------------
extern "C" void kernel_launch(void* const* d_in, const int* in_sizes, int n_in,
                              void* d_out, int out_size, void* d_ws, size_t ws_size,
                              hipStream_t stream) {
    const float* x  = (const float*)d_in[0];
    const int*   ei = (const int*)d_in[1];
    const float* ew = (const float*)d_in[2];
    const float* w1 = (const float*)d_in[3];
    const float* w2 = (const float*)d_in[4];
    const float* w3 = (const float*)d_in[5];
    float* out = (float*)d_out;

    char* w = (char*)d_ws;
    constexpr size_t CTRL_OFF  = 0;
    constexpr size_t TOK_OFF   = 4096;
    constexpr size_t ROWW_OFF  = TOK_OFF + (size_t)MAX_ROWS * 4;       // 73728
    constexpr size_t ROWOF_OFF = ROWW_OFF + (size_t)MAX_ROWS * 4;      // 143360
    constexpr size_t XB_OFF    = ROWOF_OFF + (size_t)T_TOKENS * 2 * 4; // 274432
    constexpr size_t WC_OFF    = XB_OFF + (size_t)T_TOKENS * D_MODEL * 2;       // +16 MB
    constexpr size_t W3T_OFF   = WC_OFF + (size_t)N_EXP * 4096 * 1024 * 2;      // +64 MB
    constexpr size_t H_OFF     = W3T_OFF + (size_t)N_EXP * D_MODEL * D_FF * 2;  // +32 MB
    // O2 (bf16, MAX_ROWS x D_MODEL = 35.7 MB) aliases wc (64 MB), dead after gemm1.
    constexpr size_t O2_OFF    = WC_OFF;

    int*   ctrl    = (int*)(w + CTRL_OFF);
    int*   tokenId = (int*)(w + TOK_OFF);
    float* rowW    = (float*)(w + ROWW_OFF);
    int*   rowOf   = (int*)(w + ROWOF_OFF);
    bf16*  xb      = (bf16*)(w + XB_OFF);
    bf16*  wc      = (bf16*)(w + WC_OFF);
    bf16*  w3t     = (bf16*)(w + W3T_OFF);
    bf16*  H       = (bf16*)(w + H_OFF);
    bf16*  O2      = (bf16*)(w + O2_OFF);

    prep_kernel<<<dim3(32, 32, 29), 256, 0, stream>>>(x, xb, w1, w2, w3, wc, w3t,
                                                      ei, ew, ctrl, tokenId, rowW, rowOf);
    gemm1_kernel<<<MAX_MT * (4096 / 128), 256, 0, stream>>>(xb, wc, H, ctrl, tokenId);
    gemm2_kernel<<<MAX_MT * (D_MODEL / 128), 256, 0, stream>>>(H, w3t, O2, ctrl, rowW);
    combine_kernel<<<T_TOKENS, 256, 0, stream>>>(O2, rowOf, out);
}

// Round 10
// 358.879 us; speedup vs baseline: 1.3947x; 1.0333x over previous
//
#include <hip/hip_runtime.h>
#include <hip/hip_bf16.h>
#include <cstdint>
#include <cstddef>

typedef __bf16 bf16;
typedef __attribute__((ext_vector_type(4))) float f32x4;
typedef __attribute__((ext_vector_type(8))) __bf16 bf16x8;
typedef __attribute__((ext_vector_type(4))) __bf16 bf16x4;

// ---------------- constants ----------------
#define T_TOKENS 8192
#define D_MODEL  1024
#define D_FF     2048
#define N_EXP    8
#define MAX_ROWS 17408   // 16384 + 8*128 padding
#define MAX_MT   136     // max m-tiles of 128 (8 XCD chunks of 17)

// ctrl layout (int indices): numTiles[16], pstart[32..40],
// tileExpert[64..199], tileRow[256..391]

__device__ __forceinline__ void gload16(const void* g, void* l) {
    __builtin_amdgcn_global_load_lds((const __attribute__((address_space(1))) void*)g,
                                     (__attribute__((address_space(3))) void*)l, 16, 0, 0);
}

// ---------------- fused prep: weight transposes + x convert + dispatch build ----
// grid (32,32,29), 256 threads.
//   z in [0,8):  W1 expert z   -> wc even 16-col blocks (mode 1)
//   z in [8,16): W2 expert z-8 -> wc odd 16-col blocks (mode 2)
//   z in [16,24): W3 expert z-16 -> w3t plain (mode 0)
//   z in [24,28): cvtx, virtual block (z-24)*1024 + y*32 + x
//   z == 28, block (0,0): dispatch build (count/scan/scatter/pad) in one block.
//
// Transpose tile: bf16 [64 rows][8 slots x 16B], swizzle s' = s ^ (r&7) ^ ((r>>3)&7).
//   write phase: ds_write_b64, each quarter-wave hits each bank exactly once.
//   read phase: 8 same-column lanes land in 8 distinct 4-bank groups (2 lanes/bank
//   across the wave = free per m136).
__global__ __launch_bounds__(256)
void prep_kernel(const float* __restrict__ x, bf16* __restrict__ xb,
                 const float* __restrict__ w1, const float* __restrict__ w2,
                 const float* __restrict__ w3, bf16* __restrict__ wc,
                 bf16* __restrict__ w3t,
                 const int* __restrict__ ei, const float* __restrict__ ew,
                 int* __restrict__ ctrl, int* __restrict__ tokenId,
                 float* __restrict__ rowW, int* __restrict__ rowOf) {
    const int z = blockIdx.z;
    const int t = threadIdx.x;

    if (z >= 24) {
        if (z == 28) {
            // ---- dispatch build: single block ----
            if (blockIdx.x != 0 || blockIdx.y != 0) return;
            __shared__ int lc[N_EXP], cur[N_EXP], ps[N_EXP], padS[N_EXP], padE[N_EXP];
            if (t < N_EXP) { lc[t] = 0; cur[t] = 0; }
            __syncthreads();
            for (int i = t; i < T_TOKENS * 2; i += 256)
                atomicAdd(&lc[ei[i]], 1);
            __syncthreads();
            if (t == 0) {
                int s = 0, nt = 0;
                for (int e = 0; e < N_EXP; ++e) {
                    ps[e] = s;
                    ctrl[32 + e] = s;
                    int cnt = lc[e];
                    int tiles = (cnt + 127) >> 7;
                    for (int i = 0; i < tiles; ++i) {
                        ctrl[64 + nt] = e; ctrl[256 + nt] = s + (i << 7); ++nt;
                    }
                    padS[e] = s + cnt; padE[e] = s + (tiles << 7);
                    s += tiles << 7;
                }
                ctrl[16] = nt;
            }
            __syncthreads();
            for (int i = t; i < T_TOKENS * 2; i += 256) {
                int e = ei[i];
                int pos = atomicAdd(&cur[e], 1);
                int r = ps[e] + pos;
                tokenId[r] = i >> 1;
                rowW[r] = ew[i];
                rowOf[i] = r;
            }
            for (int e = 0; e < N_EXP; ++e)
                for (int r = padS[e] + t; r < padE[e]; r += 256) {
                    tokenId[r] = 0; rowW[r] = 0.f;
                }
            return;
        }
        // ---- cvtx: x fp32 -> xb bf16, 8 elems/thread ----
        int bid = (z - 24) * 1024 + blockIdx.y * 32 + blockIdx.x;
        int i = (bid * 256 + t) * 8;
        float4 v0 = *(const float4*)(x + i);
        float4 v1 = *(const float4*)(x + i + 4);
        bf16x8 o;
        o[0] = (bf16)v0.x; o[1] = (bf16)v0.y; o[2] = (bf16)v0.z; o[3] = (bf16)v0.w;
        o[4] = (bf16)v1.x; o[5] = (bf16)v1.y; o[6] = (bf16)v1.z; o[7] = (bf16)v1.w;
        *(bf16x8*)(xb + i) = o;
        return;
    }

    // ---- tconv: fp32 [R][C] -> bf16 [f(C)][R] for one expert ----
    int R, C, mode;
    const float* src;
    bf16* dst;
    if (z < 8)       { R = D_MODEL; C = D_FF;    mode = 1; src = w1 + (size_t)z * R * C;        dst = wc  + (size_t)z * 4096 * 1024; }
    else if (z < 16) { R = D_MODEL; C = D_FF;    mode = 2; src = w2 + (size_t)(z - 8) * R * C;  dst = wc  + (size_t)(z - 8) * 4096 * 1024; }
    else             { R = D_FF;    C = D_MODEL; mode = 0; src = w3 + (size_t)(z - 16) * R * C; dst = w3t + (size_t)(z - 16) * D_FF * D_MODEL; }
    const int c0 = blockIdx.x * 64, r0 = blockIdx.y * 64;
    if (c0 >= C || r0 >= R) return;

    __shared__ char tl[8192];   // bf16 [64][8 slots x 16B], swizzled

    // phase 1: 4 independent float4 loads (row = wi>>4, col-quad = wi&15)
    float4 v[4];
#pragma unroll
    for (int p = 0; p < 4; ++p) {
        int wi = p * 256 + t;
        int rl = wi >> 4, cq = wi & 15;
        v[p] = *(const float4*)(src + (size_t)(r0 + rl) * C + c0 + cq * 4);
    }
#pragma unroll
    for (int p = 0; p < 4; ++p) {
        int wi = p * 256 + t;
        int rl = wi >> 4, cq = wi & 15;
        int sg = cq >> 1, h = cq & 1;
        int sp = sg ^ (rl & 7) ^ ((rl >> 3) & 7);
        bf16x4 o;
        o[0] = (bf16)v[p].x; o[1] = (bf16)v[p].y;
        o[2] = (bf16)v[p].z; o[3] = (bf16)v[p].w;
        *(bf16x4*)(tl + rl * 128 + sp * 16 + h * 8) = o;
    }
    __syncthreads();

    // phase 2: col = wi>>3, row-segment = wi&7; 8 scalar reads -> one 16B store
#pragma unroll
    for (int p = 0; p < 2; ++p) {
        int wi = p * 256 + t;
        int cl = wi >> 3, rs = wi & 7;
        int c = c0 + cl;
        int dcol = (mode == 0) ? c : (((c >> 4) << 5) + ((mode == 2) ? 16 : 0) + (c & 15));
        int s = cl >> 3, o_ = cl & 7;
        bf16x8 ov;
#pragma unroll
        for (int j = 0; j < 8; ++j) {
            int r = rs * 8 + j;
            int sp = s ^ (r & 7) ^ rs;      // (r>>3)&7 == rs
            ov[j] = *(const bf16*)(tl + r * 128 + sp * 16 + o_ * 2);
        }
        *(bf16x8*)(dst + (size_t)dcol * R + r0 + rs * 8) = ov;
    }
}

// ---------------- GEMM stage 1: H = silu(X Wc_even) * (X Wc_odd), gathered rows ----
// Combined B: wc [E][4096][1024] bf16 (row = combined col, K contiguous).
// m97-style 2-barrier single-buffer loop; 3 blocks/CU.
// Grid: 1D 4352 blocks, XCD-locality swizzle (xcd = L&7 owns m-tiles chunk).
__global__ __launch_bounds__(256, 3)
void gemm1_kernel(const bf16* __restrict__ xb, const bf16* __restrict__ wc,
                  bf16* __restrict__ H, const int* __restrict__ ctrl,
                  const int* __restrict__ tokenId) {
    const int L = blockIdx.x;
    const int xcd = L & 7;
    const int w = L >> 3;                 // 0..543
    const int mt = xcd * 17 + (w % 17);   // 0..135
    const int n0 = (w / 17) * 128;        // combined-col tile base (0..4095)
    if (mt >= ctrl[16]) return;
    const int e = ctrl[64 + mt];
    const int rowBase = ctrl[256 + mt];

    __shared__ char lds[32768];        // A: [0,16384)  B: [16384,32768)

    const int tid = threadIdx.x, lane = tid & 63;
    const int wm = (tid >> 7) & 1, wn = (tid >> 6) & 1;

    const bf16* wb = wc + (size_t)e * 4096 * 1024;

    const bf16* aSrc[4]; const bf16* bSrc[4]; int dstOff[4];
#pragma unroll
    for (int rd = 0; rd < 4; ++rd) {
        int o = rd * 4096 + tid * 16;
        int r = o >> 7;                    // row 0..127
        int c2 = ((o >> 4) & 7) ^ (r & 7); // pre-swizzled source slot
        dstOff[rd] = o;
        int tok = tokenId[rowBase + r];
        aSrc[rd] = xb + (size_t)tok * D_MODEL + c2 * 8;
        bSrc[rd] = wb + (size_t)(n0 + r) * D_MODEL + c2 * 8;
    }

    f32x4 acc[4][4];
#pragma unroll
    for (int m = 0; m < 4; ++m)
#pragma unroll
        for (int n = 0; n < 4; ++n) acc[m][n] = (f32x4){0.f, 0.f, 0.f, 0.f};

    for (int kt = 0; kt < D_MODEL / 64; ++kt) {
#pragma unroll
        for (int rd = 0; rd < 4; ++rd) {
            gload16(aSrc[rd] + kt * 64, lds + dstOff[rd]);
            gload16(bSrc[rd] + kt * 64, lds + 16384 + dstOff[rd]);
        }
        __syncthreads();   // drains vmcnt before any wave reads
#pragma unroll
        for (int ks = 0; ks < 2; ++ks) {
            bf16x8 af[4], bfr[4];
            int c2 = ks * 4 + (lane >> 4);
#pragma unroll
            for (int m = 0; m < 4; ++m) {
                int r = wm * 64 + m * 16 + (lane & 15);
                af[m] = *(const bf16x8*)(lds + r * 128 + ((c2 ^ (r & 7)) << 4));
            }
#pragma unroll
            for (int n = 0; n < 4; ++n) {
                int r = wn * 64 + n * 16 + (lane & 15);
                bfr[n] = *(const bf16x8*)(lds + 16384 + r * 128 + ((c2 ^ (r & 7)) << 4));
            }
#pragma unroll
            for (int m = 0; m < 4; ++m)
#pragma unroll
                for (int n = 0; n < 4; ++n)
                    acc[m][n] = __builtin_amdgcn_mfma_f32_16x16x32_bf16(af[m], bfr[n], acc[m][n], 0, 0, 0);
        }
        __syncthreads();   // all waves done reading before next stage overwrites
    }

    // epilogue: n-frag pairs (0,1)=(g,v) and (2,3)=(g,v); H col = (n0>>1)+wn*32+(pair?16:0)+(lane&15)
#pragma unroll
    for (int m = 0; m < 4; ++m) {
#pragma unroll
        for (int j = 0; j < 4; ++j) {
            int rl = wm * 64 + m * 16 + (lane >> 4) * 4 + j;
            bf16* hb = H + (size_t)(rowBase + rl) * D_FF + (n0 >> 1) + wn * 32 + (lane & 15);
            {
                float g = acc[m][0][j], v = acc[m][1][j];
                hb[0] = (bf16)((g / (1.f + __expf(-g))) * v);
            }
            {
                float g = acc[m][2][j], v = acc[m][3][j];
                hb[16] = (bf16)((g / (1.f + __expf(-g))) * v);
            }
        }
    }
}

// ---------------- GEMM stage 2: O2[row] = w[row] * (H[row] @ W3) ----------------
// Grid: 1D 1088 blocks. XCD swizzle, n-minor within chunk.
__global__ __launch_bounds__(256, 3)
void gemm2_kernel(const bf16* __restrict__ H, const bf16* __restrict__ w3t,
                  bf16* __restrict__ O2, const int* __restrict__ ctrl,
                  const float* __restrict__ rowW) {
    const int L = blockIdx.x;
    const int xcd = L & 7;
    const int w = L >> 3;                 // 0..135
    const int n0 = (w & 7) * 128;
    const int mt = xcd * 17 + (w >> 3);   // 0..135
    if (mt >= ctrl[16]) return;
    const int e = ctrl[64 + mt];
    const int rowBase = ctrl[256 + mt];

    __shared__ char lds[32768];

    const int tid = threadIdx.x, lane = tid & 63;
    const int wm = (tid >> 7) & 1, wn = (tid >> 6) & 1;

    const bf16* w3b = w3t + (size_t)e * D_MODEL * D_FF;
    const bf16* aSrc[4]; const bf16* bSrc[4]; int dstOff[4];
#pragma unroll
    for (int rd = 0; rd < 4; ++rd) {
        int o = rd * 4096 + tid * 16;
        int r = o >> 7;
        int c2 = ((o >> 4) & 7) ^ (r & 7);
        dstOff[rd] = o;
        aSrc[rd] = H   + (size_t)(rowBase + r) * D_FF + c2 * 8;
        bSrc[rd] = w3b + (size_t)(n0 + r) * D_FF + c2 * 8;
    }

    f32x4 acc[4][4];
#pragma unroll
    for (int m = 0; m < 4; ++m)
#pragma unroll
        for (int n = 0; n < 4; ++n) acc[m][n] = (f32x4){0.f, 0.f, 0.f, 0.f};

    for (int kt = 0; kt < D_FF / 64; ++kt) {
#pragma unroll
        for (int rd = 0; rd < 4; ++rd) {
            gload16(aSrc[rd] + kt * 64, lds + dstOff[rd]);
            gload16(bSrc[rd] + kt * 64, lds + 16384 + dstOff[rd]);
        }
        __syncthreads();
#pragma unroll
        for (int ks = 0; ks < 2; ++ks) {
            bf16x8 af[4], bfr[4];
            int c2 = ks * 4 + (lane >> 4);
#pragma unroll
            for (int m = 0; m < 4; ++m) {
                int r = wm * 64 + m * 16 + (lane & 15);
                af[m] = *(const bf16x8*)(lds + r * 128 + ((c2 ^ (r & 7)) << 4));
            }
#pragma unroll
            for (int n = 0; n < 4; ++n) {
                int r = wn * 64 + n * 16 + (lane & 15);
                bfr[n] = *(const bf16x8*)(lds + 16384 + r * 128 + ((c2 ^ (r & 7)) << 4));
            }
#pragma unroll
            for (int m = 0; m < 4; ++m)
#pragma unroll
                for (int n = 0; n < 4; ++n)
                    acc[m][n] = __builtin_amdgcn_mfma_f32_16x16x32_bf16(af[m], bfr[n], acc[m][n], 0, 0, 0);
        }
        __syncthreads();
    }

#pragma unroll
    for (int m = 0; m < 4; ++m) {
#pragma unroll
        for (int j = 0; j < 4; ++j) {
            int rl = wm * 64 + m * 16 + (lane >> 4) * 4 + j;
            int row = rowBase + rl;
            float wgt = rowW[row];
            bf16* obase = O2 + (size_t)row * D_MODEL + n0 + wn * 64 + (lane & 15);
#pragma unroll
            for (int n = 0; n < 4; ++n)
                obase[n * 16] = (bf16)(wgt * acc[m][n][j]);
        }
    }
}

// ---------------- combine: out[t] = O2[rowOf[t,0]] + O2[rowOf[t,1]] ----------------
__global__ void combine_kernel(const bf16* __restrict__ O2, const int* __restrict__ rowOf,
                               float* __restrict__ out) {
    int t = blockIdx.x;
    int r0 = rowOf[t * 2 + 0], r1 = rowOf[t * 2 + 1];
    int c = threadIdx.x * 4;
    bf16x4 a = *(const bf16x4*)(O2 + (size_t)r0 * D_MODEL + c);
    bf16x4 b = *(const bf16x4*)(O2 + (size_t)r1 * D_MODEL + c);
    float4 o;
    o.x = (float)a[0] + (float)b[0];
    o.y = (float)a[1] + (float)b[1];
    o.z = (float)a[2] + (float)b[2];
    o.w = (float)a[3] + (float)b[3];
    *(float4*)(out + (size_t)t * D_MODEL + c) = o;
}

// ---------------- launch ----------------
extern "C" void kernel_launch(void* const* d_in, const int* in_sizes, int n_in,
                              void* d_out, int out_size, void* d_ws, size_t ws_size,
                              hipStream_t stream) {
    const float* x  = (const float*)d_in[0];
    const int*   ei = (const int*)d_in[1];
    const float* ew = (const float*)d_in[2];
    const float* w1 = (const float*)d_in[3];
    const float* w2 = (const float*)d_in[4];
    const float* w3 = (const float*)d_in[5];
    float* out = (float*)d_out;

    char* w = (char*)d_ws;
    constexpr size_t CTRL_OFF  = 0;
    constexpr size_t TOK_OFF   = 4096;
    constexpr size_t ROWW_OFF  = TOK_OFF + (size_t)MAX_ROWS * 4;       // 73728
    constexpr size_t ROWOF_OFF = ROWW_OFF + (size_t)MAX_ROWS * 4;      // 143360
    constexpr size_t XB_OFF    = ROWOF_OFF + (size_t)T_TOKENS * 2 * 4; // 274432
    constexpr size_t WC_OFF    = XB_OFF + (size_t)T_TOKENS * D_MODEL * 2;       // +16 MB
    constexpr size_t W3T_OFF   = WC_OFF + (size_t)N_EXP * 4096 * 1024 * 2;      // +64 MB
    constexpr size_t H_OFF     = W3T_OFF + (size_t)N_EXP * D_MODEL * D_FF * 2;  // +32 MB
    // O2 (bf16, MAX_ROWS x D_MODEL = 35.7 MB) aliases wc (64 MB), dead after gemm1.
    constexpr size_t O2_OFF    = WC_OFF;

    int*   ctrl    = (int*)(w + CTRL_OFF);
    int*   tokenId = (int*)(w + TOK_OFF);
    float* rowW    = (float*)(w + ROWW_OFF);
    int*   rowOf   = (int*)(w + ROWOF_OFF);
    bf16*  xb      = (bf16*)(w + XB_OFF);
    bf16*  wc      = (bf16*)(w + WC_OFF);
    bf16*  w3t     = (bf16*)(w + W3T_OFF);
    bf16*  H       = (bf16*)(w + H_OFF);
    bf16*  O2      = (bf16*)(w + O2_OFF);

    prep_kernel<<<dim3(32, 32, 29), 256, 0, stream>>>(x, xb, w1, w2, w3, wc, w3t,
                                                      ei, ew, ctrl, tokenId, rowW, rowOf);
    gemm1_kernel<<<MAX_MT * (4096 / 128), 256, 0, stream>>>(xb, wc, H, ctrl, tokenId);
    gemm2_kernel<<<MAX_MT * (D_MODEL / 128), 256, 0, stream>>>(H, w3t, O2, ctrl, rowW);
    combine_kernel<<<T_TOKENS, 256, 0, stream>>>(O2, rowOf, out);
}